// Round 10
// baseline (811.487 us; speedup 1.0000x reference)
//
#include <hip/hip_runtime.h>
#include <hip/hip_bf16.h>

// CGCNN forward. Materialize-tbuf + swapped-operand MFMA + staged writeout + gather-hoisted k_bond:
//   t[n,m,:] = hi[n,:] + hj[idx[n,m],:] + bond[n,m,:]@w_b   (bias folded into hi)
// k_bond per tile (2 barriers):
//   I1: issue hj gathers (j prefetched last tile) + next-A staging + next-bidx -> MFMA -> t_lds
//   I2: writeout (t_lds + L1-hot hi + resident hj8 -> stats -> 16B tbuf stores), commit A[next]
// r9 lesson: __syncthreads drains vmcnt(0) -> loads only overlap work in their own interval;
//   so issue the random gather at interval START, consume after the barrier.
// r7: no direct scatter stores. r4: no min-waves clamp. r6: no analytic-mean prologue.

#define NN 40000
#define MM 12
#define AA 64
#define LL 3
#define CC 128
#define F0C 92
#define NBOND (NN*MM)
#define EPSBN 1e-5f

#define G_BOND 1250     // 7500 tiles of 64 bonds -> 6 tiles/block
#define NTILE 7500
#define G_APPLY 1250

#define L2E 1.4426950408889634f
#define LN2 0.6931471805599453f

typedef __attribute__((ext_vector_type(8))) short bf16x8;
typedef __attribute__((ext_vector_type(4))) float f32x4;

__device__ __forceinline__ float softplusf_(float x) {
    float e = __builtin_amdgcn_exp2f(-fabsf(x) * L2E);
    return fmaxf(x, 0.f) + __builtin_amdgcn_logf(1.f + e) * LN2;
}
__device__ __forceinline__ float sigmoidf_(float x) {
    return __builtin_amdgcn_rcpf(1.f + __builtin_amdgcn_exp2f(-x * L2E));
}
__device__ __forceinline__ unsigned short f2bf(float f) {
    unsigned int u = __float_as_uint(f);
    unsigned int r = (u + 0x7fffu + ((u >> 16) & 1u)) >> 16;
    return (unsigned short)r;
}
__device__ __forceinline__ float bf2f(unsigned short s) {
    return __uint_as_float(((unsigned int)s) << 16);
}

// ---------------- bond features f32 -> bf16, once ----------------
__global__ __launch_bounds__(256) void k_cvt(const float* __restrict__ in,
        unsigned short* __restrict__ out) {
    size_t i = ((size_t)blockIdx.x * 256 + threadIdx.x) * 8;
    float4 a = *(const float4*)&in[i];
    float4 b = *(const float4*)&in[i + 4];
    ushort4 ua, ub;
    ua.x = f2bf(a.x); ua.y = f2bf(a.y); ua.z = f2bf(a.z); ua.w = f2bf(a.w);
    ub.x = f2bf(b.x); ub.y = f2bf(b.y); ub.z = f2bf(b.z); ub.w = f2bf(b.w);
    *(ushort4*)&out[i] = ua;
    *(ushort4*)&out[i + 4] = ub;
}

// ---------------- fc1 ----------------
__global__ __launch_bounds__(256) void k_fc1(const float* __restrict__ site,
        const float* __restrict__ w, const float* __restrict__ b,
        float* __restrict__ h) {
    __shared__ float w_s[F0C][AA];
    __shared__ float x_s[16][F0C];
    int tid = threadIdx.x;
    for (int i = tid; i < F0C * AA; i += 256) w_s[i / AA][i % AA] = w[i];
    int n0 = blockIdx.x * 16;
    for (int i = tid; i < 16 * F0C; i += 256) x_s[i / F0C][i % F0C] = site[(size_t)n0 * F0C + i];
    __syncthreads();
    int d = tid & 63, ng = tid >> 6;
    float bb = b[d];
    float acc[4] = {bb, bb, bb, bb};
    #pragma unroll 4
    for (int k = 0; k < F0C; ++k) {
        float wv = w_s[k][d];
        acc[0] += x_s[ng][k] * wv;
        acc[1] += x_s[ng + 4][k] * wv;
        acc[2] += x_s[ng + 8][k] * wv;
        acc[3] += x_s[ng + 12][k] * wv;
    }
    #pragma unroll
    for (int rr = 0; rr < 4; ++rr)
        h[(size_t)(n0 + ng + rr * 4) * AA + d] = acc[rr];
}

// ---------------- proj: hi = h@w_i + bias, hj = h@w_j -> bf16 ----------------
__global__ __launch_bounds__(256) void k_proj(const float* __restrict__ h,
        const float* __restrict__ convw, const float* __restrict__ convb,
        unsigned short* __restrict__ hi, unsigned short* __restrict__ hj) {
    __shared__ float w_s[64][256];
    __shared__ float hT[64][36];
    int tid = threadIdx.x;
    for (int i = tid; i < 64 * 256; i += 256) {
        int k = i >> 8, c = i & 255;
        w_s[k][c] = convw[(size_t)((c < 128 ? k : 64 + k)) * 128 + (c & 127)];
    }
    int row0 = blockIdx.x * 32;
    for (int i = tid; i < 2048; i += 256) {
        int r = i >> 6, k = i & 63;
        hT[k][r] = h[(size_t)(row0 + r) * 64 + k];
    }
    __syncthreads();
    int c0 = (tid & 63) * 4;
    int r0 = (tid >> 6) * 8;
    float acc[8][4];
    #pragma unroll
    for (int r = 0; r < 8; ++r)
        #pragma unroll
        for (int i = 0; i < 4; ++i) acc[r][i] = 0.f;
    #pragma unroll 4
    for (int k = 0; k < 64; ++k) {
        float4 w4 = *(const float4*)&w_s[k][c0];
        float4 ha = *(const float4*)&hT[k][r0];
        float4 hb = *(const float4*)&hT[k][r0 + 4];
        float wv[4] = {w4.x, w4.y, w4.z, w4.w};
        float hv[8] = {ha.x, ha.y, ha.z, ha.w, hb.x, hb.y, hb.z, hb.w};
        #pragma unroll
        for (int r = 0; r < 8; ++r)
            #pragma unroll
            for (int i = 0; i < 4; ++i) acc[r][i] += hv[r] * wv[i];
    }
    bool isHi = (c0 < 128);
    int cc = isHi ? c0 : c0 - 128;
    float4 cb4 = make_float4(0.f, 0.f, 0.f, 0.f);
    if (isHi) cb4 = *(const float4*)&convb[c0];
    unsigned short* dst = isHi ? hi : hj;
    #pragma unroll
    for (int r = 0; r < 8; ++r) {
        int n = row0 + r0 + r;
        ushort4 o;
        o.x = f2bf(acc[r][0] + cb4.x);
        o.y = f2bf(acc[r][1] + cb4.y);
        o.z = f2bf(acc[r][2] + cb4.z);
        o.w = f2bf(acc[r][3] + cb4.w);
        *(ushort4*)&dst[(size_t)n * 128 + cc] = o;
    }
}

// ---------------- bond GEMM, gather-hoisted pipeline ----------------
template<bool BFQ>
__global__ __launch_bounds__(256) void k_bond(const float* __restrict__ bf,
        const unsigned short* __restrict__ bfq,
        const float* __restrict__ wb,
        const unsigned short* __restrict__ hi, const unsigned short* __restrict__ hj,
        const int* __restrict__ bidx,
        unsigned short* __restrict__ tbuf,
        float* __restrict__ part1) {
    __shared__ __align__(16) char buf0[128 * 72 * 2];      // wbT preload, then t_lds[64][140]
    __shared__ __align__(16) char bufA[2][64 * 76 * 2];    // double-buffered A; red overlays [0]
    auto wbT   = (unsigned short(*)[72])buf0;
    auto t_lds = (unsigned short(*)[140])buf0;
    auto red   = (float(*)[128])bufA[0];

    int tid = threadIdx.x;
    int lane = tid & 63, w = tid >> 6;
    int l15 = lane & 15, l4 = lane >> 4;

    for (int i = tid; i < 64 * 128; i += 256) {
        int k = i >> 7, c = i & 127;
        wbT[c][k] = f2bf(wb[i]);
    }
    __syncthreads();
    bf16x8 bfr[2][8];
    #pragma unroll
    for (int kh = 0; kh < 2; ++kh)
        #pragma unroll
        for (int ct = 0; ct < 8; ++ct)
            bfr[kh][ct] = *(const bf16x8*)&wbT[ct * 16 + l15][kh * 32 + l4 * 8];

    int myb = w * 16 + l15;                    // MFMA-phase bond
    int wr = tid >> 4, wc8 = (tid & 15) * 8;   // writeout-phase coords
    int sr = tid >> 3, sk8 = (tid & 7) * 8;    // staging coords
    float suml[8], sql[8];
    #pragma unroll
    for (int k = 0; k < 8; ++k) { suml[k] = 0.f; sql[k] = 0.f; }

    // prologue: stage tile0 into A[0]; prefetch bidx for tile0
    int j4[4];
    {
        int bond0 = blockIdx.x * 64;
        #pragma unroll
        for (int rr = 0; rr < 4; ++rr) j4[rr] = bidx[bond0 + wr + rr * 16];
        auto A0 = (unsigned short(*)[76])bufA[0];
        if constexpr (BFQ) {
            bf16x8 s0 = *(const bf16x8*)&bfq[((size_t)(bond0 + sr)) * 64 + sk8];
            bf16x8 s1 = *(const bf16x8*)&bfq[((size_t)(bond0 + sr + 32)) * 64 + sk8];
            *(bf16x8*)&A0[sr][sk8] = s0;
            *(bf16x8*)&A0[sr + 32][sk8] = s1;
        } else {
            #pragma unroll
            for (int ii = 0; ii < 2; ++ii) {
                int r = sr + ii * 32;
                float4 v0 = *(const float4*)&bf[((size_t)(bond0 + r)) * 64 + sk8];
                float4 v1 = *(const float4*)&bf[((size_t)(bond0 + r)) * 64 + sk8 + 4];
                ushort4 ua, ub;
                ua.x = f2bf(v0.x); ua.y = f2bf(v0.y); ua.z = f2bf(v0.z); ua.w = f2bf(v0.w);
                ub.x = f2bf(v1.x); ub.y = f2bf(v1.y); ub.z = f2bf(v1.z); ub.w = f2bf(v1.w);
                *(ushort4*)&A0[r][sk8] = ua;
                *(ushort4*)&A0[r][sk8 + 4] = ub;
            }
        }
    }
    __syncthreads();   // A[0] ready; bfr's wbT reads complete before t_lds overlays

    int it = 0;
    for (int tile = blockIdx.x; tile < NTILE; tile += G_BOND, ++it) {
        int bond0 = tile * 64;
        auto Acur = (unsigned short(*)[76])bufA[it & 1];
        auto Anxt = (unsigned short(*)[76])bufA[(it & 1) ^ 1];
        bool has_next = (tile + G_BOND < NTILE);

        // I1a: issue current-tile hj gathers (random rows; overlap everything below)
        bf16x8 hj8[4];
        #pragma unroll
        for (int rr = 0; rr < 4; ++rr)
            hj8[rr] = *(const bf16x8*)&hj[(size_t)j4[rr] * 128 + wc8];

        // I1b: issue next-tile staging loads + bidx prefetch
        bf16x8 st0, st1;
        float4 nf0[2], nf1[2];
        int j4n[4];
        if (has_next) {
            int nb0 = (tile + G_BOND) * 64;
            if constexpr (BFQ) {
                st0 = *(const bf16x8*)&bfq[((size_t)(nb0 + sr)) * 64 + sk8];
                st1 = *(const bf16x8*)&bfq[((size_t)(nb0 + sr + 32)) * 64 + sk8];
            } else {
                #pragma unroll
                for (int ii = 0; ii < 2; ++ii) {
                    int r = sr + ii * 32;
                    nf0[ii] = *(const float4*)&bf[((size_t)(nb0 + r)) * 64 + sk8];
                    nf1[ii] = *(const float4*)&bf[((size_t)(nb0 + r)) * 64 + sk8 + 4];
                }
            }
            #pragma unroll
            for (int rr = 0; rr < 4; ++rr) j4n[rr] = bidx[nb0 + wr + rr * 16];
        }

        // I1c: MFMA current tile
        f32x4 acc[8];
        #pragma unroll
        for (int ct = 0; ct < 8; ++ct) acc[ct] = (f32x4){0.f, 0.f, 0.f, 0.f};
        #pragma unroll
        for (int kh = 0; kh < 2; ++kh) {
            bf16x8 a = *(const bf16x8*)&Acur[myb][kh * 32 + l4 * 8];
            #pragma unroll
            for (int ct = 0; ct < 8; ++ct)
                acc[ct] = __builtin_amdgcn_mfma_f32_16x16x32_bf16(bfr[kh][ct], a, acc[ct], 0, 0, 0);
        }

        // I1d: stage raw acc (bf16) into t_lds
        #pragma unroll
        for (int ct = 0; ct < 8; ++ct) {
            ushort4 o;
            o.x = f2bf(acc[ct][0]); o.y = f2bf(acc[ct][1]);
            o.z = f2bf(acc[ct][2]); o.w = f2bf(acc[ct][3]);
            *(ushort4*)&t_lds[myb][ct * 16 + l4 * 4] = o;
        }
        __syncthreads();

        // I2a: writeout — t_lds + L1-hot hi + resident hj8; 256B store runs
        #pragma unroll
        for (int rr = 0; rr < 4; ++rr) {
            int r = wr + rr * 16;
            int bond = bond0 + r;
            int n = bond / MM;
            bf16x8 g8  = *(const bf16x8*)&t_lds[r][wc8];
            bf16x8 hi8 = *(const bf16x8*)&hi[(size_t)n * 128 + wc8];
            bf16x8 o;
            #pragma unroll
            for (int k = 0; k < 8; ++k) {
                float t = bf2f((unsigned short)g8[k]) + bf2f((unsigned short)hi8[k])
                        + bf2f((unsigned short)hj8[rr][k]);
                suml[k] += t;
                sql[k] += t * t;
                o[k] = (short)f2bf(t);
            }
            *(bf16x8*)&tbuf[(size_t)bond * 128 + wc8] = o;
        }

        // I2b: commit staged regs into A[next]; roll bidx prefetch
        if (has_next) {
            if constexpr (BFQ) {
                *(bf16x8*)&Anxt[sr][sk8] = st0;
                *(bf16x8*)&Anxt[sr + 32][sk8] = st1;
            } else {
                #pragma unroll
                for (int ii = 0; ii < 2; ++ii) {
                    int r = sr + ii * 32;
                    ushort4 ua, ub;
                    ua.x = f2bf(nf0[ii].x); ua.y = f2bf(nf0[ii].y);
                    ua.z = f2bf(nf0[ii].z); ua.w = f2bf(nf0[ii].w);
                    ub.x = f2bf(nf1[ii].x); ub.y = f2bf(nf1[ii].y);
                    ub.z = f2bf(nf1[ii].z); ub.w = f2bf(nf1[ii].w);
                    *(ushort4*)&Anxt[r][sk8] = ua;
                    *(ushort4*)&Anxt[r][sk8 + 4] = ub;
                }
            }
            #pragma unroll
            for (int rr = 0; rr < 4; ++rr) j4[rr] = j4n[rr];
        }
        __syncthreads();
    }

    // bn1 partials: thread owns cols wc8..wc8+7; reduce over 16 row-groups
    #pragma unroll
    for (int k = 0; k < 8; ++k) red[wr][wc8 + k] = suml[k];
    __syncthreads();
    if (tid < 128) {
        float s = 0.f;
        #pragma unroll
        for (int g = 0; g < 16; ++g) s += red[g][tid];
        part1[(size_t)blockIdx.x * 256 + tid] = s;
    }
    __syncthreads();
    #pragma unroll
    for (int k = 0; k < 8; ++k) red[wr][wc8 + k] = sql[k];
    __syncthreads();
    if (tid < 128) {
        float s = 0.f;
        #pragma unroll
        for (int g = 0; g < 16; ++g) s += red[g][tid];
        part1[(size_t)blockIdx.x * 256 + 128 + tid] = s;
    }
}

// ---------------- finalize bn1 (reads part1 directly, 1024 thr) ----------------
__global__ __launch_bounds__(1024) void k_fin1(const float* __restrict__ part1,
        const float* __restrict__ g, const float* __restrict__ b, float* __restrict__ scsh) {
    __shared__ float sm[4][256];
    int tid = threadIdx.x;
    int rg = tid >> 8, c = tid & 255;
    float acc = 0.f;
    for (int r = rg; r < G_BOND; r += 4) acc += part1[(size_t)r * 256 + c];
    sm[rg][c] = acc;
    __syncthreads();
    if (tid < 256) sm[0][tid] = sm[0][tid] + sm[1][tid] + sm[2][tid] + sm[3][tid];
    __syncthreads();
    if (tid < 128) {
        float m = sm[0][tid] / (float)NBOND;
        float v = sm[0][128 + tid] / (float)NBOND - m * m;
        float sc = g[tid] * rsqrtf(v + EPSBN);
        scsh[tid] = sc;
        scsh[128 + tid] = b[tid] - m * sc;
    }
}

// ---------------- finalize bn2 (reads part2 directly, 1024 thr) ----------------
__global__ __launch_bounds__(1024) void k_fin2(const float* __restrict__ part2,
        const float* __restrict__ g, const float* __restrict__ b, float* __restrict__ scsh2) {
    __shared__ float sm[8][128];
    int tid = threadIdx.x;
    int rg = tid >> 7, c = tid & 127;
    float acc = 0.f;
    for (int r = rg; r < G_APPLY; r += 8) acc += part2[(size_t)r * 128 + c];
    sm[rg][c] = acc;
    __syncthreads();
    if (tid < 128) {
        float s = 0.f;
        #pragma unroll
        for (int g8 = 0; g8 < 8; ++g8) s += sm[g8][tid];
        sm[0][tid] = s;
    }
    __syncthreads();
    if (tid < 64) {
        float m = sm[0][tid] / (float)NN;
        float v = sm[0][64 + tid] / (float)NN - m * m;
        float sc = g[tid] * rsqrtf(v + EPSBN);
        scsh2[tid] = sc;
        scsh2[64 + tid] = b[tid] - m * sc;
    }
}

// ---------------- apply bn1 + gated sum over m + bn2 partial stats ----------------
__global__ __launch_bounds__(256) void k_apply(const unsigned short* __restrict__ tbuf,
        const float* __restrict__ scsh, float* __restrict__ s_out,
        float* __restrict__ part2) {
    __shared__ float red[32][64];
    int tid = threadIdx.x;
    int c8 = (tid & 7) * 8, sg = tid >> 3;
    float scf[8], shf[8], scc[8], shc[8];
    #pragma unroll
    for (int j = 0; j < 8; ++j) {
        scf[j] = scsh[c8 + j];       shf[j] = scsh[128 + c8 + j];
        scc[j] = scsh[64 + c8 + j];  shc[j] = scsh[192 + c8 + j];
    }
    float sum[8], sq[8];
    #pragma unroll
    for (int j = 0; j < 8; ++j) { sum[j] = 0.f; sq[j] = 0.f; }
    for (int q = blockIdx.x; q < NN / 32; q += G_APPLY) {
        int n = q * 32 + sg;
        const unsigned short* tb = tbuf + (size_t)n * (MM * 128);
        float sacc[8];
        #pragma unroll
        for (int j = 0; j < 8; ++j) sacc[j] = 0.f;
        #pragma unroll
        for (int m = 0; m < MM; ++m) {
            bf16x8 f8 = *(const bf16x8*)&tb[m * 128 + c8];
            bf16x8 s8 = *(const bf16x8*)&tb[m * 128 + 64 + c8];
            #pragma unroll
            for (int j = 0; j < 8; ++j) {
                float ff = bf2f((unsigned short)f8[j]);
                float ss = bf2f((unsigned short)s8[j]);
                sacc[j] += sigmoidf_(scf[j] * ff + shf[j]) * softplusf_(scc[j] * ss + shc[j]);
            }
        }
        float4 oa = make_float4(sacc[0], sacc[1], sacc[2], sacc[3]);
        float4 ob = make_float4(sacc[4], sacc[5], sacc[6], sacc[7]);
        *(float4*)&s_out[(size_t)n * 64 + c8] = oa;
        *(float4*)&s_out[(size_t)n * 64 + c8 + 4] = ob;
        #pragma unroll
        for (int j = 0; j < 8; ++j) { sum[j] += sacc[j]; sq[j] += sacc[j] * sacc[j]; }
    }
    #pragma unroll
    for (int j = 0; j < 8; ++j) red[sg][c8 + j] = sum[j];
    __syncthreads();
    if (tid < 64) {
        float t = 0.f;
        #pragma unroll
        for (int g = 0; g < 32; ++g) t += red[g][tid];
        part2[(size_t)blockIdx.x * 128 + tid] = t;
    }
    __syncthreads();
    #pragma unroll
    for (int j = 0; j < 8; ++j) red[sg][c8 + j] = sq[j];
    __syncthreads();
    if (tid < 64) {
        float t = 0.f;
        #pragma unroll
        for (int g = 0; g < 32; ++g) t += red[g][tid];
        part2[(size_t)blockIdx.x * 128 + 64 + tid] = t;
    }
}

// ---------------- h = softplus(h + bn2(s)) ----------------
__global__ __launch_bounds__(256) void k_upd(float* __restrict__ h, const float* __restrict__ s,
        const float* __restrict__ scsh2) {
    size_t i = ((size_t)blockIdx.x * 256 + threadIdx.x) * 4;
    int c0 = (int)(i & 63);
    float4 hv = *(const float4*)&h[i];
    float4 sv = *(const float4*)&s[i];
    float4 o;
    o.x = softplusf_(hv.x + scsh2[c0 + 0] * sv.x + scsh2[64 + c0 + 0]);
    o.y = softplusf_(hv.y + scsh2[c0 + 1] * sv.y + scsh2[64 + c0 + 1]);
    o.z = softplusf_(hv.z + scsh2[c0 + 2] * sv.z + scsh2[64 + c0 + 2]);
    o.w = softplusf_(hv.w + scsh2[c0 + 3] * sv.w + scsh2[64 + c0 + 3]);
    *(float4*)&h[i] = o;
}

// ---------------- pooling ----------------
__device__ __forceinline__ int lbound(const int* a, int n, int v) {
    int lo = 0, hi = n;
    while (lo < hi) { int mid = (lo + hi) >> 1; if (a[mid] < v) lo = mid + 1; else hi = mid; }
    return lo;
}

__global__ __launch_bounds__(256) void k_pool(const float* __restrict__ h,
        const int* __restrict__ cidx, float* __restrict__ feats) {
    __shared__ float red[4][68];
    __shared__ int bounds[2];
    int c = blockIdx.x, tid = threadIdx.x;
    if (tid == 0) {
        bounds[0] = lbound(cidx, NN, c);
        bounds[1] = lbound(cidx, NN, c + 1);
    }
    __syncthreads();
    int lo = bounds[0], hi = bounds[1];
    int d = tid & 63, g = tid >> 6;
    float acc = 0;
    for (int n = lo + g; n < hi; n += 4) acc += h[(size_t)n * 64 + d];
    red[g][d] = acc;
    __syncthreads();
    if (tid < 64) {
        float t = red[0][tid] + red[1][tid] + red[2][tid] + red[3][tid];
        int cnt = hi - lo;
        feats[(size_t)c * 65 + tid] = t / (float)(cnt > 0 ? cnt : 1);
    }
}

// ---------------- head ----------------
__global__ __launch_bounds__(128) void k_head1(float* __restrict__ feats, const float* __restrict__ fap,
        const float* __restrict__ g, const float* __restrict__ b, float* __restrict__ featsp) {
    int tid = threadIdx.x;
    if (tid < CC) feats[(size_t)tid * 65 + 64] = fap[tid];
    __syncthreads();
    if (tid < 65) {
        float s = 0;
        for (int r = 0; r < CC; ++r) s += feats[r * 65 + tid];
        float m = s / (float)CC;
        float v = 0;
        for (int r = 0; r < CC; ++r) { float d = feats[r * 65 + tid] - m; v += d * d; }
        v /= (float)CC;
        float sc = g[tid] * rsqrtf(v + EPSBN);
        float sh = b[tid] - m * sc;
        for (int r = 0; r < CC; ++r)
            featsp[r * 65 + tid] = softplusf_(sc * feats[r * 65 + tid] + sh);
    }
}

__global__ __launch_bounds__(128) void k_head2(const float* __restrict__ featsp,
        const float* __restrict__ fc2w, const float* __restrict__ fc2b,
        const float* __restrict__ fc3w, const float* __restrict__ fc3b,
        float* __restrict__ out) {
    __shared__ float fr[65];
    __shared__ float red[128];
    int r = blockIdx.x, tid = threadIdx.x;
    if (tid < 65) fr[tid] = featsp[(size_t)r * 65 + tid];
    __syncthreads();
    float acc = fc2b[tid];
    for (int k = 0; k < 65; ++k) acc += fr[k] * fc2w[k * 128 + tid];
    red[tid] = softplusf_(acc) * fc3w[tid];
    __syncthreads();
    for (int st = 64; st > 0; st >>= 1) {
        if (tid < st) red[tid] += red[tid + st];
        __syncthreads();
    }
    if (tid == 0) out[r] = red[0] + fc3b[0];
}

extern "C" void kernel_launch(void* const* d_in, const int* in_sizes, int n_in,
                              void* d_out, int out_size, void* d_ws, size_t ws_size,
                              hipStream_t stream) {
    const float* site  = (const float*)d_in[0];
    const float* bondf = (const float*)d_in[1];
    const float* fap   = (const float*)d_in[2];
    const float* fc1w  = (const float*)d_in[3];
    const float* fc1b  = (const float*)d_in[4];
    const float* convw = (const float*)d_in[5];
    const float* convb = (const float*)d_in[6];
    const float* bn1g  = (const float*)d_in[7];
    const float* bn1b  = (const float*)d_in[8];
    const float* bn2g  = (const float*)d_in[9];
    const float* bn2b  = (const float*)d_in[10];
    const float* topg  = (const float*)d_in[11];
    const float* topb  = (const float*)d_in[12];
    const float* fc2w  = (const float*)d_in[13];
    const float* fc2b  = (const float*)d_in[14];
    const float* fc3w  = (const float*)d_in[15];
    const float* fc3b  = (const float*)d_in[16];
    const int*   bidx  = (const int*)d_in[17];
    const int*   cidx  = (const int*)d_in[18];
    float* out = (float*)d_out;

    char* w = (char*)d_ws;
    constexpr size_t SZ_H  = (size_t)NN * 64 * 4;
    constexpr size_t SZ_HP = (size_t)NN * 128 * 2;   // hi/hj bf16
    constexpr size_t OFF_H  = 0;
    constexpr size_t OFF_HI = OFF_H + SZ_H;
    constexpr size_t OFF_HJ = OFF_HI + SZ_HP;
    constexpr size_t OFF_S  = OFF_HJ + SZ_HP;
    constexpr size_t OFF_SCSH1 = OFF_S + SZ_H;
    constexpr size_t OFF_SCSH2 = OFF_SCSH1 + 1024;
    constexpr size_t OFF_P1 = OFF_SCSH2 + 512;
    constexpr size_t OFF_P2 = OFF_P1 + (size_t)G_BOND * 256 * 4;
    constexpr size_t OFF_FE = OFF_P2 + (size_t)G_APPLY * 128 * 4;
    constexpr size_t OFF_FP = OFF_FE + 128 * 65 * 4;
    constexpr size_t OFF_T  = ((OFF_FP + 128 * 65 * 4) + 255) & ~(size_t)255;
    constexpr size_t OFF_BFQ = OFF_T + (size_t)NBOND * 128 * 2;
    constexpr size_t NEED_BFQ = OFF_BFQ + (size_t)NBOND * 64 * 2;

    float* h      = (float*)(w + OFF_H);
    unsigned short* hi = (unsigned short*)(w + OFF_HI);
    unsigned short* hj = (unsigned short*)(w + OFF_HJ);
    float* sbuf   = (float*)(w + OFF_S);
    float* scsh1  = (float*)(w + OFF_SCSH1);
    float* scsh2  = (float*)(w + OFF_SCSH2);
    float* part1  = (float*)(w + OFF_P1);
    float* part2  = (float*)(w + OFF_P2);
    float* feats  = (float*)(w + OFF_FE);
    float* featsp = (float*)(w + OFF_FP);
    unsigned short* tbuf = (unsigned short*)(w + OFF_T);
    unsigned short* bfq  = (unsigned short*)(w + OFF_BFQ);

    const bool useq = (ws_size >= NEED_BFQ);

    if (useq) k_cvt<<<NBOND * 64 / (256 * 8), 256, 0, stream>>>(bondf, bfq);
    k_fc1<<<2500, 256, 0, stream>>>(site, fc1w, fc1b, h);
    for (int l = 0; l < LL; ++l) {
        const float* cw = convw + (size_t)l * 192 * 128;
        const float* cb = convb + l * 128;
        k_proj<<<1250, 256, 0, stream>>>(h, cw, cb, hi, hj);
        if (useq)
            k_bond<true><<<G_BOND, 256, 0, stream>>>(bondf, bfq, cw + 128 * 128, hi, hj, bidx, tbuf, part1);
        else
            k_bond<false><<<G_BOND, 256, 0, stream>>>(bondf, bfq, cw + 128 * 128, hi, hj, bidx, tbuf, part1);
        k_fin1<<<1, 1024, 0, stream>>>(part1, bn1g + l * 128, bn1b + l * 128, scsh1);
        k_apply<<<G_APPLY, 256, 0, stream>>>(tbuf, scsh1, sbuf, part2);
        k_fin2<<<1, 1024, 0, stream>>>(part2, bn2g + l * 64, bn2b + l * 64, scsh2);
        k_upd<<<2500, 256, 0, stream>>>(h, sbuf, scsh2);
    }
    k_pool<<<128, 256, 0, stream>>>(h, cidx, feats);
    k_head1<<<1, 128, 0, stream>>>(feats, fap, topg, topb, featsp);
    k_head2<<<128, 128, 0, stream>>>(featsp, fc2w, fc2b, fc3w, fc3b, out);
}

// Round 11
// 506.084 us; speedup vs baseline: 1.6035x; 1.6035x over previous
//
#include <hip/hip_runtime.h>
#include <hip/hip_bf16.h>

// CGCNN forward. Materialize-tbuf + swapped-operand MFMA + staged writeout + gather-hoisted k_bond.
// r10 lesson: single-block serial reductions are latency-bound (86us for 1.2MB!) -- keep the
// two-stage parallel reduction (125 blocks), finalize with row-parallel 1024-thr block.
// r9 lesson: __syncthreads drains vmcnt(0) -> issue random gathers at interval START.
// r7: no direct scatter stores. r4: no min-waves clamp. r6: no analytic-mean prologue.

#define NN 40000
#define MM 12
#define AA 64
#define LL 3
#define CC 128
#define F0C 92
#define NBOND (NN*MM)
#define EPSBN 1e-5f

#define G_BOND 1250     // 7500 tiles of 64 bonds -> 6 tiles/block
#define NTILE 7500
#define G_APPLY 1250
#define RED_B 125

#define L2E 1.4426950408889634f
#define LN2 0.6931471805599453f

typedef __attribute__((ext_vector_type(8))) short bf16x8;
typedef __attribute__((ext_vector_type(4))) float f32x4;

__device__ __forceinline__ float softplusf_(float x) {
    float e = __builtin_amdgcn_exp2f(-fabsf(x) * L2E);
    return fmaxf(x, 0.f) + __builtin_amdgcn_logf(1.f + e) * LN2;
}
__device__ __forceinline__ float sigmoidf_(float x) {
    return __builtin_amdgcn_rcpf(1.f + __builtin_amdgcn_exp2f(-x * L2E));
}
__device__ __forceinline__ unsigned short f2bf(float f) {
    unsigned int u = __float_as_uint(f);
    unsigned int r = (u + 0x7fffu + ((u >> 16) & 1u)) >> 16;
    return (unsigned short)r;
}
__device__ __forceinline__ float bf2f(unsigned short s) {
    return __uint_as_float(((unsigned int)s) << 16);
}

// ---------------- bond features f32 -> bf16, once ----------------
__global__ __launch_bounds__(256) void k_cvt(const float* __restrict__ in,
        unsigned short* __restrict__ out) {
    size_t i = ((size_t)blockIdx.x * 256 + threadIdx.x) * 8;
    float4 a = *(const float4*)&in[i];
    float4 b = *(const float4*)&in[i + 4];
    ushort4 ua, ub;
    ua.x = f2bf(a.x); ua.y = f2bf(a.y); ua.z = f2bf(a.z); ua.w = f2bf(a.w);
    ub.x = f2bf(b.x); ub.y = f2bf(b.y); ub.z = f2bf(b.z); ub.w = f2bf(b.w);
    *(ushort4*)&out[i] = ua;
    *(ushort4*)&out[i + 4] = ub;
}

// ---------------- fc1 ----------------
__global__ __launch_bounds__(256) void k_fc1(const float* __restrict__ site,
        const float* __restrict__ w, const float* __restrict__ b,
        float* __restrict__ h) {
    __shared__ float w_s[F0C][AA];
    __shared__ float x_s[16][F0C];
    int tid = threadIdx.x;
    for (int i = tid; i < F0C * AA; i += 256) w_s[i / AA][i % AA] = w[i];
    int n0 = blockIdx.x * 16;
    for (int i = tid; i < 16 * F0C; i += 256) x_s[i / F0C][i % F0C] = site[(size_t)n0 * F0C + i];
    __syncthreads();
    int d = tid & 63, ng = tid >> 6;
    float bb = b[d];
    float acc[4] = {bb, bb, bb, bb};
    #pragma unroll 4
    for (int k = 0; k < F0C; ++k) {
        float wv = w_s[k][d];
        acc[0] += x_s[ng][k] * wv;
        acc[1] += x_s[ng + 4][k] * wv;
        acc[2] += x_s[ng + 8][k] * wv;
        acc[3] += x_s[ng + 12][k] * wv;
    }
    #pragma unroll
    for (int rr = 0; rr < 4; ++rr)
        h[(size_t)(n0 + ng + rr * 4) * AA + d] = acc[rr];
}

// ---------------- proj: hi = h@w_i + bias, hj = h@w_j -> bf16 ----------------
__global__ __launch_bounds__(256) void k_proj(const float* __restrict__ h,
        const float* __restrict__ convw, const float* __restrict__ convb,
        unsigned short* __restrict__ hi, unsigned short* __restrict__ hj) {
    __shared__ float w_s[64][256];
    __shared__ float hT[64][36];
    int tid = threadIdx.x;
    for (int i = tid; i < 64 * 256; i += 256) {
        int k = i >> 8, c = i & 255;
        w_s[k][c] = convw[(size_t)((c < 128 ? k : 64 + k)) * 128 + (c & 127)];
    }
    int row0 = blockIdx.x * 32;
    for (int i = tid; i < 2048; i += 256) {
        int r = i >> 6, k = i & 63;
        hT[k][r] = h[(size_t)(row0 + r) * 64 + k];
    }
    __syncthreads();
    int c0 = (tid & 63) * 4;
    int r0 = (tid >> 6) * 8;
    float acc[8][4];
    #pragma unroll
    for (int r = 0; r < 8; ++r)
        #pragma unroll
        for (int i = 0; i < 4; ++i) acc[r][i] = 0.f;
    #pragma unroll 4
    for (int k = 0; k < 64; ++k) {
        float4 w4 = *(const float4*)&w_s[k][c0];
        float4 ha = *(const float4*)&hT[k][r0];
        float4 hb = *(const float4*)&hT[k][r0 + 4];
        float wv[4] = {w4.x, w4.y, w4.z, w4.w};
        float hv[8] = {ha.x, ha.y, ha.z, ha.w, hb.x, hb.y, hb.z, hb.w};
        #pragma unroll
        for (int r = 0; r < 8; ++r)
            #pragma unroll
            for (int i = 0; i < 4; ++i) acc[r][i] += hv[r] * wv[i];
    }
    bool isHi = (c0 < 128);
    int cc = isHi ? c0 : c0 - 128;
    float4 cb4 = make_float4(0.f, 0.f, 0.f, 0.f);
    if (isHi) cb4 = *(const float4*)&convb[c0];
    unsigned short* dst = isHi ? hi : hj;
    #pragma unroll
    for (int r = 0; r < 8; ++r) {
        int n = row0 + r0 + r;
        ushort4 o;
        o.x = f2bf(acc[r][0] + cb4.x);
        o.y = f2bf(acc[r][1] + cb4.y);
        o.z = f2bf(acc[r][2] + cb4.z);
        o.w = f2bf(acc[r][3] + cb4.w);
        *(ushort4*)&dst[(size_t)n * 128 + cc] = o;
    }
}

// ---------------- bond GEMM, gather-hoisted pipeline ----------------
template<bool BFQ>
__global__ __launch_bounds__(256) void k_bond(const float* __restrict__ bf,
        const unsigned short* __restrict__ bfq,
        const float* __restrict__ wb,
        const unsigned short* __restrict__ hi, const unsigned short* __restrict__ hj,
        const int* __restrict__ bidx,
        unsigned short* __restrict__ tbuf,
        float* __restrict__ part1) {
    __shared__ __align__(16) char buf0[128 * 72 * 2];      // wbT preload, then t_lds[64][140]
    __shared__ __align__(16) char bufA[2][64 * 76 * 2];    // double-buffered A; red overlays [0]
    auto wbT   = (unsigned short(*)[72])buf0;
    auto t_lds = (unsigned short(*)[140])buf0;
    auto red   = (float(*)[128])bufA[0];

    int tid = threadIdx.x;
    int lane = tid & 63, w = tid >> 6;
    int l15 = lane & 15, l4 = lane >> 4;

    for (int i = tid; i < 64 * 128; i += 256) {
        int k = i >> 7, c = i & 127;
        wbT[c][k] = f2bf(wb[i]);
    }
    __syncthreads();
    bf16x8 bfr[2][8];
    #pragma unroll
    for (int kh = 0; kh < 2; ++kh)
        #pragma unroll
        for (int ct = 0; ct < 8; ++ct)
            bfr[kh][ct] = *(const bf16x8*)&wbT[ct * 16 + l15][kh * 32 + l4 * 8];

    int myb = w * 16 + l15;                    // MFMA-phase bond
    int wr = tid >> 4, wc8 = (tid & 15) * 8;   // writeout-phase coords
    int sr = tid >> 3, sk8 = (tid & 7) * 8;    // staging coords
    float suml[8], sql[8];
    #pragma unroll
    for (int k = 0; k < 8; ++k) { suml[k] = 0.f; sql[k] = 0.f; }

    // prologue: stage tile0 into A[0]; prefetch bidx for tile0
    int j4[4];
    {
        int bond0 = blockIdx.x * 64;
        #pragma unroll
        for (int rr = 0; rr < 4; ++rr) j4[rr] = bidx[bond0 + wr + rr * 16];
        auto A0 = (unsigned short(*)[76])bufA[0];
        if constexpr (BFQ) {
            bf16x8 s0 = *(const bf16x8*)&bfq[((size_t)(bond0 + sr)) * 64 + sk8];
            bf16x8 s1 = *(const bf16x8*)&bfq[((size_t)(bond0 + sr + 32)) * 64 + sk8];
            *(bf16x8*)&A0[sr][sk8] = s0;
            *(bf16x8*)&A0[sr + 32][sk8] = s1;
        } else {
            #pragma unroll
            for (int ii = 0; ii < 2; ++ii) {
                int r = sr + ii * 32;
                float4 v0 = *(const float4*)&bf[((size_t)(bond0 + r)) * 64 + sk8];
                float4 v1 = *(const float4*)&bf[((size_t)(bond0 + r)) * 64 + sk8 + 4];
                ushort4 ua, ub;
                ua.x = f2bf(v0.x); ua.y = f2bf(v0.y); ua.z = f2bf(v0.z); ua.w = f2bf(v0.w);
                ub.x = f2bf(v1.x); ub.y = f2bf(v1.y); ub.z = f2bf(v1.z); ub.w = f2bf(v1.w);
                *(ushort4*)&A0[r][sk8] = ua;
                *(ushort4*)&A0[r][sk8 + 4] = ub;
            }
        }
    }
    __syncthreads();   // A[0] ready; bfr's wbT reads complete before t_lds overlays

    int it = 0;
    for (int tile = blockIdx.x; tile < NTILE; tile += G_BOND, ++it) {
        int bond0 = tile * 64;
        auto Acur = (unsigned short(*)[76])bufA[it & 1];
        auto Anxt = (unsigned short(*)[76])bufA[(it & 1) ^ 1];
        bool has_next = (tile + G_BOND < NTILE);

        // I1a: issue current-tile hj gathers (random rows; overlap everything below)
        bf16x8 hj8[4];
        #pragma unroll
        for (int rr = 0; rr < 4; ++rr)
            hj8[rr] = *(const bf16x8*)&hj[(size_t)j4[rr] * 128 + wc8];

        // I1b: issue next-tile staging loads + bidx prefetch
        bf16x8 st0, st1;
        float4 nf0[2], nf1[2];
        int j4n[4];
        if (has_next) {
            int nb0 = (tile + G_BOND) * 64;
            if constexpr (BFQ) {
                st0 = *(const bf16x8*)&bfq[((size_t)(nb0 + sr)) * 64 + sk8];
                st1 = *(const bf16x8*)&bfq[((size_t)(nb0 + sr + 32)) * 64 + sk8];
            } else {
                #pragma unroll
                for (int ii = 0; ii < 2; ++ii) {
                    int r = sr + ii * 32;
                    nf0[ii] = *(const float4*)&bf[((size_t)(nb0 + r)) * 64 + sk8];
                    nf1[ii] = *(const float4*)&bf[((size_t)(nb0 + r)) * 64 + sk8 + 4];
                }
            }
            #pragma unroll
            for (int rr = 0; rr < 4; ++rr) j4n[rr] = bidx[nb0 + wr + rr * 16];
        }

        // I1c: MFMA current tile
        f32x4 acc[8];
        #pragma unroll
        for (int ct = 0; ct < 8; ++ct) acc[ct] = (f32x4){0.f, 0.f, 0.f, 0.f};
        #pragma unroll
        for (int kh = 0; kh < 2; ++kh) {
            bf16x8 a = *(const bf16x8*)&Acur[myb][kh * 32 + l4 * 8];
            #pragma unroll
            for (int ct = 0; ct < 8; ++ct)
                acc[ct] = __builtin_amdgcn_mfma_f32_16x16x32_bf16(bfr[kh][ct], a, acc[ct], 0, 0, 0);
        }

        // I1d: stage raw acc (bf16) into t_lds
        #pragma unroll
        for (int ct = 0; ct < 8; ++ct) {
            ushort4 o;
            o.x = f2bf(acc[ct][0]); o.y = f2bf(acc[ct][1]);
            o.z = f2bf(acc[ct][2]); o.w = f2bf(acc[ct][3]);
            *(ushort4*)&t_lds[myb][ct * 16 + l4 * 4] = o;
        }
        __syncthreads();

        // I2a: writeout — t_lds + L1-hot hi + resident hj8; 256B store runs
        #pragma unroll
        for (int rr = 0; rr < 4; ++rr) {
            int r = wr + rr * 16;
            int bond = bond0 + r;
            int n = bond / MM;
            bf16x8 g8  = *(const bf16x8*)&t_lds[r][wc8];
            bf16x8 hi8 = *(const bf16x8*)&hi[(size_t)n * 128 + wc8];
            bf16x8 o;
            #pragma unroll
            for (int k = 0; k < 8; ++k) {
                float t = bf2f((unsigned short)g8[k]) + bf2f((unsigned short)hi8[k])
                        + bf2f((unsigned short)hj8[rr][k]);
                suml[k] += t;
                sql[k] += t * t;
                o[k] = (short)f2bf(t);
            }
            *(bf16x8*)&tbuf[(size_t)bond * 128 + wc8] = o;
        }

        // I2b: commit staged regs into A[next]; roll bidx prefetch
        if (has_next) {
            if constexpr (BFQ) {
                *(bf16x8*)&Anxt[sr][sk8] = st0;
                *(bf16x8*)&Anxt[sr + 32][sk8] = st1;
            } else {
                #pragma unroll
                for (int ii = 0; ii < 2; ++ii) {
                    int r = sr + ii * 32;
                    ushort4 ua, ub;
                    ua.x = f2bf(nf0[ii].x); ua.y = f2bf(nf0[ii].y);
                    ua.z = f2bf(nf0[ii].z); ua.w = f2bf(nf0[ii].w);
                    ub.x = f2bf(nf1[ii].x); ub.y = f2bf(nf1[ii].y);
                    ub.z = f2bf(nf1[ii].z); ub.w = f2bf(nf1[ii].w);
                    *(ushort4*)&Anxt[r][sk8] = ua;
                    *(ushort4*)&Anxt[r][sk8 + 4] = ub;
                }
            }
            #pragma unroll
            for (int rr = 0; rr < 4; ++rr) j4[rr] = j4n[rr];
        }
        __syncthreads();
    }

    // bn1 partials: thread owns cols wc8..wc8+7; reduce over 16 row-groups
    #pragma unroll
    for (int k = 0; k < 8; ++k) red[wr][wc8 + k] = suml[k];
    __syncthreads();
    if (tid < 128) {
        float s = 0.f;
        #pragma unroll
        for (int g = 0; g < 16; ++g) s += red[g][tid];
        part1[(size_t)blockIdx.x * 256 + tid] = s;
    }
    __syncthreads();
    #pragma unroll
    for (int k = 0; k < 8; ++k) red[wr][wc8 + k] = sql[k];
    __syncthreads();
    if (tid < 128) {
        float s = 0.f;
        #pragma unroll
        for (int g = 0; g < 16; ++g) s += red[g][tid];
        part1[(size_t)blockIdx.x * 256 + 128 + tid] = s;
    }
}

// ---------------- stage-A reductions: [1250][W] -> [125][W], parallel ----------------
__global__ __launch_bounds__(256) void k_red1(const float* __restrict__ in, float* __restrict__ out) {
    int tid = threadIdx.x, b = blockIdx.x;
    float acc = 0.f;
    for (int r = b * 10; r < b * 10 + 10; ++r) acc += in[(size_t)r * 256 + tid];
    out[(size_t)b * 256 + tid] = acc;
}
__global__ __launch_bounds__(128) void k_red2(const float* __restrict__ in, float* __restrict__ out) {
    int tid = threadIdx.x, b = blockIdx.x;
    float acc = 0.f;
    for (int r = b * 10; r < b * 10 + 10; ++r) acc += in[(size_t)r * 128 + tid];
    out[(size_t)b * 128 + tid] = acc;
}

// ---------------- finalize bn1 (row-parallel over 125 partials) ----------------
__global__ __launch_bounds__(1024) void k_fin1(const float* __restrict__ partA,
        const float* __restrict__ g, const float* __restrict__ b, float* __restrict__ scsh) {
    __shared__ float sm[4][256];
    int tid = threadIdx.x;
    int rg = tid >> 8, c = tid & 255;
    float acc = 0.f;
    for (int r = rg; r < RED_B; r += 4) acc += partA[(size_t)r * 256 + c];
    sm[rg][c] = acc;
    __syncthreads();
    if (tid < 256) sm[0][tid] = sm[0][tid] + sm[1][tid] + sm[2][tid] + sm[3][tid];
    __syncthreads();
    if (tid < 128) {
        float m = sm[0][tid] / (float)NBOND;
        float v = sm[0][128 + tid] / (float)NBOND - m * m;
        float sc = g[tid] * rsqrtf(v + EPSBN);
        scsh[tid] = sc;
        scsh[128 + tid] = b[tid] - m * sc;
    }
}

// ---------------- finalize bn2 (row-parallel over 125 partials) ----------------
__global__ __launch_bounds__(1024) void k_fin2(const float* __restrict__ partB,
        const float* __restrict__ g, const float* __restrict__ b, float* __restrict__ scsh2) {
    __shared__ float sm[8][128];
    int tid = threadIdx.x;
    int rg = tid >> 7, c = tid & 127;
    float acc = 0.f;
    for (int r = rg; r < RED_B; r += 8) acc += partB[(size_t)r * 128 + c];
    sm[rg][c] = acc;
    __syncthreads();
    if (tid < 128) {
        float s = 0.f;
        #pragma unroll
        for (int g8 = 0; g8 < 8; ++g8) s += sm[g8][tid];
        sm[0][tid] = s;
    }
    __syncthreads();
    if (tid < 64) {
        float m = sm[0][tid] / (float)NN;
        float v = sm[0][64 + tid] / (float)NN - m * m;
        float sc = g[tid] * rsqrtf(v + EPSBN);
        scsh2[tid] = sc;
        scsh2[64 + tid] = b[tid] - m * sc;
    }
}

// ---------------- apply bn1 + gated sum over m + bn2 partial stats ----------------
__global__ __launch_bounds__(256) void k_apply(const unsigned short* __restrict__ tbuf,
        const float* __restrict__ scsh, float* __restrict__ s_out,
        float* __restrict__ part2) {
    __shared__ float red[32][64];
    int tid = threadIdx.x;
    int c8 = (tid & 7) * 8, sg = tid >> 3;
    float scf[8], shf[8], scc[8], shc[8];
    #pragma unroll
    for (int j = 0; j < 8; ++j) {
        scf[j] = scsh[c8 + j];       shf[j] = scsh[128 + c8 + j];
        scc[j] = scsh[64 + c8 + j];  shc[j] = scsh[192 + c8 + j];
    }
    float sum[8], sq[8];
    #pragma unroll
    for (int j = 0; j < 8; ++j) { sum[j] = 0.f; sq[j] = 0.f; }
    for (int q = blockIdx.x; q < NN / 32; q += G_APPLY) {
        int n = q * 32 + sg;
        const unsigned short* tb = tbuf + (size_t)n * (MM * 128);
        float sacc[8];
        #pragma unroll
        for (int j = 0; j < 8; ++j) sacc[j] = 0.f;
        #pragma unroll
        for (int m = 0; m < MM; ++m) {
            bf16x8 f8 = *(const bf16x8*)&tb[m * 128 + c8];
            bf16x8 s8 = *(const bf16x8*)&tb[m * 128 + 64 + c8];
            #pragma unroll
            for (int j = 0; j < 8; ++j) {
                float ff = bf2f((unsigned short)f8[j]);
                float ss = bf2f((unsigned short)s8[j]);
                sacc[j] += sigmoidf_(scf[j] * ff + shf[j]) * softplusf_(scc[j] * ss + shc[j]);
            }
        }
        float4 oa = make_float4(sacc[0], sacc[1], sacc[2], sacc[3]);
        float4 ob = make_float4(sacc[4], sacc[5], sacc[6], sacc[7]);
        *(float4*)&s_out[(size_t)n * 64 + c8] = oa;
        *(float4*)&s_out[(size_t)n * 64 + c8 + 4] = ob;
        #pragma unroll
        for (int j = 0; j < 8; ++j) { sum[j] += sacc[j]; sq[j] += sacc[j] * sacc[j]; }
    }
    #pragma unroll
    for (int j = 0; j < 8; ++j) red[sg][c8 + j] = sum[j];
    __syncthreads();
    if (tid < 64) {
        float t = 0.f;
        #pragma unroll
        for (int g = 0; g < 32; ++g) t += red[g][tid];
        part2[(size_t)blockIdx.x * 128 + tid] = t;
    }
    __syncthreads();
    #pragma unroll
    for (int j = 0; j < 8; ++j) red[sg][c8 + j] = sq[j];
    __syncthreads();
    if (tid < 64) {
        float t = 0.f;
        #pragma unroll
        for (int g = 0; g < 32; ++g) t += red[g][tid];
        part2[(size_t)blockIdx.x * 128 + 64 + tid] = t;
    }
}

// ---------------- h = softplus(h + bn2(s)) ----------------
__global__ __launch_bounds__(256) void k_upd(float* __restrict__ h, const float* __restrict__ s,
        const float* __restrict__ scsh2) {
    size_t i = ((size_t)blockIdx.x * 256 + threadIdx.x) * 4;
    int c0 = (int)(i & 63);
    float4 hv = *(const float4*)&h[i];
    float4 sv = *(const float4*)&s[i];
    float4 o;
    o.x = softplusf_(hv.x + scsh2[c0 + 0] * sv.x + scsh2[64 + c0 + 0]);
    o.y = softplusf_(hv.y + scsh2[c0 + 1] * sv.y + scsh2[64 + c0 + 1]);
    o.z = softplusf_(hv.z + scsh2[c0 + 2] * sv.z + scsh2[64 + c0 + 2]);
    o.w = softplusf_(hv.w + scsh2[c0 + 3] * sv.w + scsh2[64 + c0 + 3]);
    *(float4*)&h[i] = o;
}

// ---------------- pooling ----------------
__device__ __forceinline__ int lbound(const int* a, int n, int v) {
    int lo = 0, hi = n;
    while (lo < hi) { int mid = (lo + hi) >> 1; if (a[mid] < v) lo = mid + 1; else hi = mid; }
    return lo;
}

__global__ __launch_bounds__(256) void k_pool(const float* __restrict__ h,
        const int* __restrict__ cidx, float* __restrict__ feats) {
    __shared__ float red[4][68];
    __shared__ int bounds[2];
    int c = blockIdx.x, tid = threadIdx.x;
    if (tid == 0) {
        bounds[0] = lbound(cidx, NN, c);
        bounds[1] = lbound(cidx, NN, c + 1);
    }
    __syncthreads();
    int lo = bounds[0], hi = bounds[1];
    int d = tid & 63, g = tid >> 6;
    float acc = 0;
    for (int n = lo + g; n < hi; n += 4) acc += h[(size_t)n * 64 + d];
    red[g][d] = acc;
    __syncthreads();
    if (tid < 64) {
        float t = red[0][tid] + red[1][tid] + red[2][tid] + red[3][tid];
        int cnt = hi - lo;
        feats[(size_t)c * 65 + tid] = t / (float)(cnt > 0 ? cnt : 1);
    }
}

// ---------------- head ----------------
__global__ __launch_bounds__(128) void k_head1(float* __restrict__ feats, const float* __restrict__ fap,
        const float* __restrict__ g, const float* __restrict__ b, float* __restrict__ featsp) {
    int tid = threadIdx.x;
    if (tid < CC) feats[(size_t)tid * 65 + 64] = fap[tid];
    __syncthreads();
    if (tid < 65) {
        float s = 0;
        for (int r = 0; r < CC; ++r) s += feats[r * 65 + tid];
        float m = s / (float)CC;
        float v = 0;
        for (int r = 0; r < CC; ++r) { float d = feats[r * 65 + tid] - m; v += d * d; }
        v /= (float)CC;
        float sc = g[tid] * rsqrtf(v + EPSBN);
        float sh = b[tid] - m * sc;
        for (int r = 0; r < CC; ++r)
            featsp[r * 65 + tid] = softplusf_(sc * feats[r * 65 + tid] + sh);
    }
}

__global__ __launch_bounds__(128) void k_head2(const float* __restrict__ featsp,
        const float* __restrict__ fc2w, const float* __restrict__ fc2b,
        const float* __restrict__ fc3w, const float* __restrict__ fc3b,
        float* __restrict__ out) {
    __shared__ float fr[65];
    __shared__ float red[128];
    int r = blockIdx.x, tid = threadIdx.x;
    if (tid < 65) fr[tid] = featsp[(size_t)r * 65 + tid];
    __syncthreads();
    float acc = fc2b[tid];
    for (int k = 0; k < 65; ++k) acc += fr[k] * fc2w[k * 128 + tid];
    red[tid] = softplusf_(acc) * fc3w[tid];
    __syncthreads();
    for (int st = 64; st > 0; st >>= 1) {
        if (tid < st) red[tid] += red[tid + st];
        __syncthreads();
    }
    if (tid == 0) out[r] = red[0] + fc3b[0];
}

extern "C" void kernel_launch(void* const* d_in, const int* in_sizes, int n_in,
                              void* d_out, int out_size, void* d_ws, size_t ws_size,
                              hipStream_t stream) {
    const float* site  = (const float*)d_in[0];
    const float* bondf = (const float*)d_in[1];
    const float* fap   = (const float*)d_in[2];
    const float* fc1w  = (const float*)d_in[3];
    const float* fc1b  = (const float*)d_in[4];
    const float* convw = (const float*)d_in[5];
    const float* convb = (const float*)d_in[6];
    const float* bn1g  = (const float*)d_in[7];
    const float* bn1b  = (const float*)d_in[8];
    const float* bn2g  = (const float*)d_in[9];
    const float* bn2b  = (const float*)d_in[10];
    const float* topg  = (const float*)d_in[11];
    const float* topb  = (const float*)d_in[12];
    const float* fc2w  = (const float*)d_in[13];
    const float* fc2b  = (const float*)d_in[14];
    const float* fc3w  = (const float*)d_in[15];
    const float* fc3b  = (const float*)d_in[16];
    const int*   bidx  = (const int*)d_in[17];
    const int*   cidx  = (const int*)d_in[18];
    float* out = (float*)d_out;

    char* w = (char*)d_ws;
    constexpr size_t SZ_H  = (size_t)NN * 64 * 4;
    constexpr size_t SZ_HP = (size_t)NN * 128 * 2;   // hi/hj bf16
    constexpr size_t OFF_H  = 0;
    constexpr size_t OFF_HI = OFF_H + SZ_H;
    constexpr size_t OFF_HJ = OFF_HI + SZ_HP;
    constexpr size_t OFF_S  = OFF_HJ + SZ_HP;
    constexpr size_t OFF_SCSH1 = OFF_S + SZ_H;
    constexpr size_t OFF_SCSH2 = OFF_SCSH1 + 1024;
    constexpr size_t OFF_P1 = OFF_SCSH2 + 512;
    constexpr size_t OFF_P2 = OFF_P1 + (size_t)G_BOND * 256 * 4;
    constexpr size_t OFF_PA = OFF_P2 + (size_t)G_APPLY * 128 * 4;
    constexpr size_t OFF_PB = OFF_PA + (size_t)RED_B * 256 * 4;
    constexpr size_t OFF_FE = OFF_PB + (size_t)RED_B * 128 * 4;
    constexpr size_t OFF_FP = OFF_FE + 128 * 65 * 4;
    constexpr size_t OFF_T  = ((OFF_FP + 128 * 65 * 4) + 255) & ~(size_t)255;
    constexpr size_t OFF_BFQ = OFF_T + (size_t)NBOND * 128 * 2;
    constexpr size_t NEED_BFQ = OFF_BFQ + (size_t)NBOND * 64 * 2;

    float* h      = (float*)(w + OFF_H);
    unsigned short* hi = (unsigned short*)(w + OFF_HI);
    unsigned short* hj = (unsigned short*)(w + OFF_HJ);
    float* sbuf   = (float*)(w + OFF_S);
    float* scsh1  = (float*)(w + OFF_SCSH1);
    float* scsh2  = (float*)(w + OFF_SCSH2);
    float* part1  = (float*)(w + OFF_P1);
    float* part2  = (float*)(w + OFF_P2);
    float* partA  = (float*)(w + OFF_PA);
    float* partB  = (float*)(w + OFF_PB);
    float* feats  = (float*)(w + OFF_FE);
    float* featsp = (float*)(w + OFF_FP);
    unsigned short* tbuf = (unsigned short*)(w + OFF_T);
    unsigned short* bfq  = (unsigned short*)(w + OFF_BFQ);

    const bool useq = (ws_size >= NEED_BFQ);

    if (useq) k_cvt<<<NBOND * 64 / (256 * 8), 256, 0, stream>>>(bondf, bfq);
    k_fc1<<<2500, 256, 0, stream>>>(site, fc1w, fc1b, h);
    for (int l = 0; l < LL; ++l) {
        const float* cw = convw + (size_t)l * 192 * 128;
        const float* cb = convb + l * 128;
        k_proj<<<1250, 256, 0, stream>>>(h, cw, cb, hi, hj);
        if (useq)
            k_bond<true><<<G_BOND, 256, 0, stream>>>(bondf, bfq, cw + 128 * 128, hi, hj, bidx, tbuf, part1);
        else
            k_bond<false><<<G_BOND, 256, 0, stream>>>(bondf, bfq, cw + 128 * 128, hi, hj, bidx, tbuf, part1);
        k_red1<<<RED_B, 256, 0, stream>>>(part1, partA);
        k_fin1<<<1, 1024, 0, stream>>>(partA, bn1g + l * 128, bn1b + l * 128, scsh1);
        k_apply<<<G_APPLY, 256, 0, stream>>>(tbuf, scsh1, sbuf, part2);
        k_red2<<<RED_B, 128, 0, stream>>>(part2, partB);
        k_fin2<<<1, 1024, 0, stream>>>(partB, bn2g + l * 64, bn2b + l * 64, scsh2);
        k_upd<<<2500, 256, 0, stream>>>(h, sbuf, scsh2);
    }
    k_pool<<<128, 256, 0, stream>>>(h, cidx, feats);
    k_head1<<<1, 128, 0, stream>>>(feats, fap, topg, topb, featsp);
    k_head2<<<128, 128, 0, stream>>>(featsp, fc2w, fc2b, fc3w, fc3b, out);
}

// Round 12
// 492.944 us; speedup vs baseline: 1.6462x; 1.0267x over previous
//
#include <hip/hip_runtime.h>
#include <hip/hip_bf16.h>

// CGCNN forward. Materialize-tbuf + swapped-operand MFMA + staged writeout + gather-hoisted k_bond.
// r12: fuse k_upd into next-layer k_proj (phase-A residual update in registers -> hT direct),
//      G_BOND=1024 (= resident blocks, no queued tail).
// r10: parallel two-stage BN reductions (single-block serial scans are latency death).
// r9:  __syncthreads drains vmcnt(0) -> issue random gathers at interval START.
// r7:  no direct scatter stores. r4: no min-waves clamp. r6: no analytic-mean prologue.

#define NN 40000
#define MM 12
#define AA 64
#define LL 3
#define CC 128
#define F0C 92
#define NBOND (NN*MM)
#define EPSBN 1e-5f

#define G_BOND 1024     // resident-exact; 7500 tiles grid-strided
#define NTILE 7500
#define G_APPLY 1250
#define RED1B 128       // part1 rows 1024 -> 128 blocks x 8 rows
#define RED2B 125       // part2 rows 1250 -> 125 blocks x 10 rows

#define L2E 1.4426950408889634f
#define LN2 0.6931471805599453f

typedef __attribute__((ext_vector_type(8))) short bf16x8;
typedef __attribute__((ext_vector_type(4))) float f32x4;

__device__ __forceinline__ float softplusf_(float x) {
    float e = __builtin_amdgcn_exp2f(-fabsf(x) * L2E);
    return fmaxf(x, 0.f) + __builtin_amdgcn_logf(1.f + e) * LN2;
}
__device__ __forceinline__ float sigmoidf_(float x) {
    return __builtin_amdgcn_rcpf(1.f + __builtin_amdgcn_exp2f(-x * L2E));
}
__device__ __forceinline__ unsigned short f2bf(float f) {
    unsigned int u = __float_as_uint(f);
    unsigned int r = (u + 0x7fffu + ((u >> 16) & 1u)) >> 16;
    return (unsigned short)r;
}
__device__ __forceinline__ float bf2f(unsigned short s) {
    return __uint_as_float(((unsigned int)s) << 16);
}

// ---------------- bond features f32 -> bf16, once ----------------
__global__ __launch_bounds__(256) void k_cvt(const float* __restrict__ in,
        unsigned short* __restrict__ out) {
    size_t i = ((size_t)blockIdx.x * 256 + threadIdx.x) * 8;
    float4 a = *(const float4*)&in[i];
    float4 b = *(const float4*)&in[i + 4];
    ushort4 ua, ub;
    ua.x = f2bf(a.x); ua.y = f2bf(a.y); ua.z = f2bf(a.z); ua.w = f2bf(a.w);
    ub.x = f2bf(b.x); ub.y = f2bf(b.y); ub.z = f2bf(b.z); ub.w = f2bf(b.w);
    *(ushort4*)&out[i] = ua;
    *(ushort4*)&out[i + 4] = ub;
}

// ---------------- fc1 ----------------
__global__ __launch_bounds__(256) void k_fc1(const float* __restrict__ site,
        const float* __restrict__ w, const float* __restrict__ b,
        float* __restrict__ h) {
    __shared__ float w_s[F0C][AA];
    __shared__ float x_s[16][F0C];
    int tid = threadIdx.x;
    for (int i = tid; i < F0C * AA; i += 256) w_s[i / AA][i % AA] = w[i];
    int n0 = blockIdx.x * 16;
    for (int i = tid; i < 16 * F0C; i += 256) x_s[i / F0C][i % F0C] = site[(size_t)n0 * F0C + i];
    __syncthreads();
    int d = tid & 63, ng = tid >> 6;
    float bb = b[d];
    float acc[4] = {bb, bb, bb, bb};
    #pragma unroll 4
    for (int k = 0; k < F0C; ++k) {
        float wv = w_s[k][d];
        acc[0] += x_s[ng][k] * wv;
        acc[1] += x_s[ng + 4][k] * wv;
        acc[2] += x_s[ng + 8][k] * wv;
        acc[3] += x_s[ng + 12][k] * wv;
    }
    #pragma unroll
    for (int rr = 0; rr < 4; ++rr)
        h[(size_t)(n0 + ng + rr * 4) * AA + d] = acc[rr];
}

// ---------------- proj (optionally fused with previous layer's h-update) ----------------
// FUSED: h' = softplus(h + bn2(s)) computed in regs, written to h (in-place, row-exclusive)
//        and into hT directly; then hi/hj projection as usual.
template<bool FUSED>
__global__ __launch_bounds__(256) void k_proj(float* __restrict__ h,
        const float* __restrict__ sbuf, const float* __restrict__ scsh2,
        const float* __restrict__ convw, const float* __restrict__ convb,
        unsigned short* __restrict__ hi, unsigned short* __restrict__ hj) {
    __shared__ float w_s[64][256];
    __shared__ float hT[64][36];
    int tid = threadIdx.x;
    int row0 = blockIdx.x * 32;
    for (int i = tid; i < 64 * 256; i += 256) {
        int k = i >> 8, c = i & 255;
        w_s[k][c] = convw[(size_t)((c < 128 ? k : 64 + k)) * 128 + (c & 127)];
    }
    if constexpr (FUSED) {
        int r = tid >> 3, k8 = (tid & 7) * 8;
        int n = row0 + r;
        float4 h0 = *(const float4*)&h[(size_t)n * 64 + k8];
        float4 h1 = *(const float4*)&h[(size_t)n * 64 + k8 + 4];
        float4 s0 = *(const float4*)&sbuf[(size_t)n * 64 + k8];
        float4 s1 = *(const float4*)&sbuf[(size_t)n * 64 + k8 + 4];
        float hv[8] = {h0.x, h0.y, h0.z, h0.w, h1.x, h1.y, h1.z, h1.w};
        float sv[8] = {s0.x, s0.y, s0.z, s0.w, s1.x, s1.y, s1.z, s1.w};
        float ov[8];
        #pragma unroll
        for (int j = 0; j < 8; ++j) {
            ov[j] = softplusf_(hv[j] + scsh2[k8 + j] * sv[j] + scsh2[64 + k8 + j]);
            hT[k8 + j][r] = ov[j];
        }
        *(float4*)&h[(size_t)n * 64 + k8]     = make_float4(ov[0], ov[1], ov[2], ov[3]);
        *(float4*)&h[(size_t)n * 64 + k8 + 4] = make_float4(ov[4], ov[5], ov[6], ov[7]);
    } else {
        for (int i = tid; i < 2048; i += 256) {
            int r = i >> 6, k = i & 63;
            hT[k][r] = h[(size_t)(row0 + r) * 64 + k];
        }
    }
    __syncthreads();
    int c0 = (tid & 63) * 4;
    int r0 = (tid >> 6) * 8;
    float acc[8][4];
    #pragma unroll
    for (int r = 0; r < 8; ++r)
        #pragma unroll
        for (int i = 0; i < 4; ++i) acc[r][i] = 0.f;
    #pragma unroll 4
    for (int k = 0; k < 64; ++k) {
        float4 w4 = *(const float4*)&w_s[k][c0];
        float4 ha = *(const float4*)&hT[k][r0];
        float4 hb = *(const float4*)&hT[k][r0 + 4];
        float wv[4] = {w4.x, w4.y, w4.z, w4.w};
        float hv[8] = {ha.x, ha.y, ha.z, ha.w, hb.x, hb.y, hb.z, hb.w};
        #pragma unroll
        for (int r = 0; r < 8; ++r)
            #pragma unroll
            for (int i = 0; i < 4; ++i) acc[r][i] += hv[r] * wv[i];
    }
    bool isHi = (c0 < 128);
    int cc = isHi ? c0 : c0 - 128;
    float4 cb4 = make_float4(0.f, 0.f, 0.f, 0.f);
    if (isHi) cb4 = *(const float4*)&convb[c0];
    unsigned short* dst = isHi ? hi : hj;
    #pragma unroll
    for (int r = 0; r < 8; ++r) {
        int n = row0 + r0 + r;
        ushort4 o;
        o.x = f2bf(acc[r][0] + cb4.x);
        o.y = f2bf(acc[r][1] + cb4.y);
        o.z = f2bf(acc[r][2] + cb4.z);
        o.w = f2bf(acc[r][3] + cb4.w);
        *(ushort4*)&dst[(size_t)n * 128 + cc] = o;
    }
}

// ---------------- bond GEMM, gather-hoisted pipeline ----------------
template<bool BFQ>
__global__ __launch_bounds__(256) void k_bond(const float* __restrict__ bf,
        const unsigned short* __restrict__ bfq,
        const float* __restrict__ wb,
        const unsigned short* __restrict__ hi, const unsigned short* __restrict__ hj,
        const int* __restrict__ bidx,
        unsigned short* __restrict__ tbuf,
        float* __restrict__ part1) {
    __shared__ __align__(16) char buf0[128 * 72 * 2];      // wbT preload, then t_lds[64][140]
    __shared__ __align__(16) char bufA[2][64 * 76 * 2];    // double-buffered A; red overlays [0]
    auto wbT   = (unsigned short(*)[72])buf0;
    auto t_lds = (unsigned short(*)[140])buf0;
    auto red   = (float(*)[128])bufA[0];

    int tid = threadIdx.x;
    int lane = tid & 63, w = tid >> 6;
    int l15 = lane & 15, l4 = lane >> 4;

    for (int i = tid; i < 64 * 128; i += 256) {
        int k = i >> 7, c = i & 127;
        wbT[c][k] = f2bf(wb[i]);
    }
    __syncthreads();
    bf16x8 bfr[2][8];
    #pragma unroll
    for (int kh = 0; kh < 2; ++kh)
        #pragma unroll
        for (int ct = 0; ct < 8; ++ct)
            bfr[kh][ct] = *(const bf16x8*)&wbT[ct * 16 + l15][kh * 32 + l4 * 8];

    int myb = w * 16 + l15;                    // MFMA-phase bond
    int wr = tid >> 4, wc8 = (tid & 15) * 8;   // writeout-phase coords
    int sr = tid >> 3, sk8 = (tid & 7) * 8;    // staging coords
    float suml[8], sql[8];
    #pragma unroll
    for (int k = 0; k < 8; ++k) { suml[k] = 0.f; sql[k] = 0.f; }

    // prologue: stage tile0 into A[0]; prefetch bidx for tile0
    int j4[4];
    {
        int bond0 = blockIdx.x * 64;
        #pragma unroll
        for (int rr = 0; rr < 4; ++rr) j4[rr] = bidx[bond0 + wr + rr * 16];
        auto A0 = (unsigned short(*)[76])bufA[0];
        if constexpr (BFQ) {
            bf16x8 s0 = *(const bf16x8*)&bfq[((size_t)(bond0 + sr)) * 64 + sk8];
            bf16x8 s1 = *(const bf16x8*)&bfq[((size_t)(bond0 + sr + 32)) * 64 + sk8];
            *(bf16x8*)&A0[sr][sk8] = s0;
            *(bf16x8*)&A0[sr + 32][sk8] = s1;
        } else {
            #pragma unroll
            for (int ii = 0; ii < 2; ++ii) {
                int r = sr + ii * 32;
                float4 v0 = *(const float4*)&bf[((size_t)(bond0 + r)) * 64 + sk8];
                float4 v1 = *(const float4*)&bf[((size_t)(bond0 + r)) * 64 + sk8 + 4];
                ushort4 ua, ub;
                ua.x = f2bf(v0.x); ua.y = f2bf(v0.y); ua.z = f2bf(v0.z); ua.w = f2bf(v0.w);
                ub.x = f2bf(v1.x); ub.y = f2bf(v1.y); ub.z = f2bf(v1.z); ub.w = f2bf(v1.w);
                *(ushort4*)&A0[r][sk8] = ua;
                *(ushort4*)&A0[r][sk8 + 4] = ub;
            }
        }
    }
    __syncthreads();   // A[0] ready; bfr's wbT reads complete before t_lds overlays

    int it = 0;
    for (int tile = blockIdx.x; tile < NTILE; tile += G_BOND, ++it) {
        int bond0 = tile * 64;
        auto Acur = (unsigned short(*)[76])bufA[it & 1];
        auto Anxt = (unsigned short(*)[76])bufA[(it & 1) ^ 1];
        bool has_next = (tile + G_BOND < NTILE);

        // I1a: issue current-tile hj gathers (random rows; overlap everything below)
        bf16x8 hj8[4];
        #pragma unroll
        for (int rr = 0; rr < 4; ++rr)
            hj8[rr] = *(const bf16x8*)&hj[(size_t)j4[rr] * 128 + wc8];

        // I1b: issue next-tile staging loads + bidx prefetch
        bf16x8 st0, st1;
        float4 nf0[2], nf1[2];
        int j4n[4];
        if (has_next) {
            int nb0 = (tile + G_BOND) * 64;
            if constexpr (BFQ) {
                st0 = *(const bf16x8*)&bfq[((size_t)(nb0 + sr)) * 64 + sk8];
                st1 = *(const bf16x8*)&bfq[((size_t)(nb0 + sr + 32)) * 64 + sk8];
            } else {
                #pragma unroll
                for (int ii = 0; ii < 2; ++ii) {
                    int r = sr + ii * 32;
                    nf0[ii] = *(const float4*)&bf[((size_t)(nb0 + r)) * 64 + sk8];
                    nf1[ii] = *(const float4*)&bf[((size_t)(nb0 + r)) * 64 + sk8 + 4];
                }
            }
            #pragma unroll
            for (int rr = 0; rr < 4; ++rr) j4n[rr] = bidx[nb0 + wr + rr * 16];
        }

        // I1c: MFMA current tile
        f32x4 acc[8];
        #pragma unroll
        for (int ct = 0; ct < 8; ++ct) acc[ct] = (f32x4){0.f, 0.f, 0.f, 0.f};
        #pragma unroll
        for (int kh = 0; kh < 2; ++kh) {
            bf16x8 a = *(const bf16x8*)&Acur[myb][kh * 32 + l4 * 8];
            #pragma unroll
            for (int ct = 0; ct < 8; ++ct)
                acc[ct] = __builtin_amdgcn_mfma_f32_16x16x32_bf16(bfr[kh][ct], a, acc[ct], 0, 0, 0);
        }

        // I1d: stage raw acc (bf16) into t_lds
        #pragma unroll
        for (int ct = 0; ct < 8; ++ct) {
            ushort4 o;
            o.x = f2bf(acc[ct][0]); o.y = f2bf(acc[ct][1]);
            o.z = f2bf(acc[ct][2]); o.w = f2bf(acc[ct][3]);
            *(ushort4*)&t_lds[myb][ct * 16 + l4 * 4] = o;
        }
        __syncthreads();

        // I2a: writeout — t_lds + L1-hot hi + resident hj8; 256B store runs
        #pragma unroll
        for (int rr = 0; rr < 4; ++rr) {
            int r = wr + rr * 16;
            int bond = bond0 + r;
            int n = bond / MM;
            bf16x8 g8  = *(const bf16x8*)&t_lds[r][wc8];
            bf16x8 hi8 = *(const bf16x8*)&hi[(size_t)n * 128 + wc8];
            bf16x8 o;
            #pragma unroll
            for (int k = 0; k < 8; ++k) {
                float t = bf2f((unsigned short)g8[k]) + bf2f((unsigned short)hi8[k])
                        + bf2f((unsigned short)hj8[rr][k]);
                suml[k] += t;
                sql[k] += t * t;
                o[k] = (short)f2bf(t);
            }
            *(bf16x8*)&tbuf[(size_t)bond * 128 + wc8] = o;
        }

        // I2b: commit staged regs into A[next]; roll bidx prefetch
        if (has_next) {
            if constexpr (BFQ) {
                *(bf16x8*)&Anxt[sr][sk8] = st0;
                *(bf16x8*)&Anxt[sr + 32][sk8] = st1;
            } else {
                #pragma unroll
                for (int ii = 0; ii < 2; ++ii) {
                    int r = sr + ii * 32;
                    ushort4 ua, ub;
                    ua.x = f2bf(nf0[ii].x); ua.y = f2bf(nf0[ii].y);
                    ua.z = f2bf(nf0[ii].z); ua.w = f2bf(nf0[ii].w);
                    ub.x = f2bf(nf1[ii].x); ub.y = f2bf(nf1[ii].y);
                    ub.z = f2bf(nf1[ii].z); ub.w = f2bf(nf1[ii].w);
                    *(ushort4*)&Anxt[r][sk8] = ua;
                    *(ushort4*)&Anxt[r][sk8 + 4] = ub;
                }
            }
            #pragma unroll
            for (int rr = 0; rr < 4; ++rr) j4[rr] = j4n[rr];
        }
        __syncthreads();
    }

    // bn1 partials: thread owns cols wc8..wc8+7; reduce over 16 row-groups
    #pragma unroll
    for (int k = 0; k < 8; ++k) red[wr][wc8 + k] = suml[k];
    __syncthreads();
    if (tid < 128) {
        float s = 0.f;
        #pragma unroll
        for (int g = 0; g < 16; ++g) s += red[g][tid];
        part1[(size_t)blockIdx.x * 256 + tid] = s;
    }
    __syncthreads();
    #pragma unroll
    for (int k = 0; k < 8; ++k) red[wr][wc8 + k] = sql[k];
    __syncthreads();
    if (tid < 128) {
        float s = 0.f;
        #pragma unroll
        for (int g = 0; g < 16; ++g) s += red[g][tid];
        part1[(size_t)blockIdx.x * 256 + 128 + tid] = s;
    }
}

// ---------------- stage-A reductions (parallel) ----------------
__global__ __launch_bounds__(256) void k_red1(const float* __restrict__ in, float* __restrict__ out) {
    int tid = threadIdx.x, b = blockIdx.x;
    float acc = 0.f;
    for (int r = b * 8; r < b * 8 + 8; ++r) acc += in[(size_t)r * 256 + tid];
    out[(size_t)b * 256 + tid] = acc;
}
__global__ __launch_bounds__(128) void k_red2(const float* __restrict__ in, float* __restrict__ out) {
    int tid = threadIdx.x, b = blockIdx.x;
    float acc = 0.f;
    for (int r = b * 10; r < b * 10 + 10; ++r) acc += in[(size_t)r * 128 + tid];
    out[(size_t)b * 128 + tid] = acc;
}

// ---------------- finalize bn1 (row-parallel over 128 partials) ----------------
__global__ __launch_bounds__(1024) void k_fin1(const float* __restrict__ partA,
        const float* __restrict__ g, const float* __restrict__ b, float* __restrict__ scsh) {
    __shared__ float sm[4][256];
    int tid = threadIdx.x;
    int rg = tid >> 8, c = tid & 255;
    float acc = 0.f;
    for (int r = rg; r < RED1B; r += 4) acc += partA[(size_t)r * 256 + c];
    sm[rg][c] = acc;
    __syncthreads();
    if (tid < 256) sm[0][tid] = sm[0][tid] + sm[1][tid] + sm[2][tid] + sm[3][tid];
    __syncthreads();
    if (tid < 128) {
        float m = sm[0][tid] / (float)NBOND;
        float v = sm[0][128 + tid] / (float)NBOND - m * m;
        float sc = g[tid] * rsqrtf(v + EPSBN);
        scsh[tid] = sc;
        scsh[128 + tid] = b[tid] - m * sc;
    }
}

// ---------------- finalize bn2 (row-parallel over 125 partials) ----------------
__global__ __launch_bounds__(1024) void k_fin2(const float* __restrict__ partB,
        const float* __restrict__ g, const float* __restrict__ b, float* __restrict__ scsh2) {
    __shared__ float sm[8][128];
    int tid = threadIdx.x;
    int rg = tid >> 7, c = tid & 127;
    float acc = 0.f;
    for (int r = rg; r < RED2B; r += 8) acc += partB[(size_t)r * 128 + c];
    sm[rg][c] = acc;
    __syncthreads();
    if (tid < 128) {
        float s = 0.f;
        #pragma unroll
        for (int g8 = 0; g8 < 8; ++g8) s += sm[g8][tid];
        sm[0][tid] = s;
    }
    __syncthreads();
    if (tid < 64) {
        float m = sm[0][tid] / (float)NN;
        float v = sm[0][64 + tid] / (float)NN - m * m;
        float sc = g[tid] * rsqrtf(v + EPSBN);
        scsh2[tid] = sc;
        scsh2[64 + tid] = b[tid] - m * sc;
    }
}

// ---------------- apply bn1 + gated sum over m + bn2 partial stats ----------------
__global__ __launch_bounds__(256) void k_apply(const unsigned short* __restrict__ tbuf,
        const float* __restrict__ scsh, float* __restrict__ s_out,
        float* __restrict__ part2) {
    __shared__ float red[32][64];
    int tid = threadIdx.x;
    int c8 = (tid & 7) * 8, sg = tid >> 3;
    float scf[8], shf[8], scc[8], shc[8];
    #pragma unroll
    for (int j = 0; j < 8; ++j) {
        scf[j] = scsh[c8 + j];       shf[j] = scsh[128 + c8 + j];
        scc[j] = scsh[64 + c8 + j];  shc[j] = scsh[192 + c8 + j];
    }
    float sum[8], sq[8];
    #pragma unroll
    for (int j = 0; j < 8; ++j) { sum[j] = 0.f; sq[j] = 0.f; }
    for (int q = blockIdx.x; q < NN / 32; q += G_APPLY) {
        int n = q * 32 + sg;
        const unsigned short* tb = tbuf + (size_t)n * (MM * 128);
        float sacc[8];
        #pragma unroll
        for (int j = 0; j < 8; ++j) sacc[j] = 0.f;
        #pragma unroll
        for (int m = 0; m < MM; ++m) {
            bf16x8 f8 = *(const bf16x8*)&tb[m * 128 + c8];
            bf16x8 s8 = *(const bf16x8*)&tb[m * 128 + 64 + c8];
            #pragma unroll
            for (int j = 0; j < 8; ++j) {
                float ff = bf2f((unsigned short)f8[j]);
                float ss = bf2f((unsigned short)s8[j]);
                sacc[j] += sigmoidf_(scf[j] * ff + shf[j]) * softplusf_(scc[j] * ss + shc[j]);
            }
        }
        float4 oa = make_float4(sacc[0], sacc[1], sacc[2], sacc[3]);
        float4 ob = make_float4(sacc[4], sacc[5], sacc[6], sacc[7]);
        *(float4*)&s_out[(size_t)n * 64 + c8] = oa;
        *(float4*)&s_out[(size_t)n * 64 + c8 + 4] = ob;
        #pragma unroll
        for (int j = 0; j < 8; ++j) { sum[j] += sacc[j]; sq[j] += sacc[j] * sacc[j]; }
    }
    #pragma unroll
    for (int j = 0; j < 8; ++j) red[sg][c8 + j] = sum[j];
    __syncthreads();
    if (tid < 64) {
        float t = 0.f;
        #pragma unroll
        for (int g = 0; g < 32; ++g) t += red[g][tid];
        part2[(size_t)blockIdx.x * 128 + tid] = t;
    }
    __syncthreads();
    #pragma unroll
    for (int j = 0; j < 8; ++j) red[sg][c8 + j] = sq[j];
    __syncthreads();
    if (tid < 64) {
        float t = 0.f;
        #pragma unroll
        for (int g = 0; g < 32; ++g) t += red[g][tid];
        part2[(size_t)blockIdx.x * 128 + 64 + tid] = t;
    }
}

// ---------------- standalone h = softplus(h + bn2(s))  (final layer only) ----------------
__global__ __launch_bounds__(256) void k_upd(float* __restrict__ h, const float* __restrict__ s,
        const float* __restrict__ scsh2) {
    size_t i = ((size_t)blockIdx.x * 256 + threadIdx.x) * 4;
    int c0 = (int)(i & 63);
    float4 hv = *(const float4*)&h[i];
    float4 sv = *(const float4*)&s[i];
    float4 o;
    o.x = softplusf_(hv.x + scsh2[c0 + 0] * sv.x + scsh2[64 + c0 + 0]);
    o.y = softplusf_(hv.y + scsh2[c0 + 1] * sv.y + scsh2[64 + c0 + 1]);
    o.z = softplusf_(hv.z + scsh2[c0 + 2] * sv.z + scsh2[64 + c0 + 2]);
    o.w = softplusf_(hv.w + scsh2[c0 + 3] * sv.w + scsh2[64 + c0 + 3]);
    *(float4*)&h[i] = o;
}

// ---------------- pooling ----------------
__device__ __forceinline__ int lbound(const int* a, int n, int v) {
    int lo = 0, hi = n;
    while (lo < hi) { int mid = (lo + hi) >> 1; if (a[mid] < v) lo = mid + 1; else hi = mid; }
    return lo;
}

__global__ __launch_bounds__(256) void k_pool(const float* __restrict__ h,
        const int* __restrict__ cidx, float* __restrict__ feats) {
    __shared__ float red[4][68];
    __shared__ int bounds[2];
    int c = blockIdx.x, tid = threadIdx.x;
    if (tid == 0) {
        bounds[0] = lbound(cidx, NN, c);
        bounds[1] = lbound(cidx, NN, c + 1);
    }
    __syncthreads();
    int lo = bounds[0], hi = bounds[1];
    int d = tid & 63, g = tid >> 6;
    float acc = 0;
    for (int n = lo + g; n < hi; n += 4) acc += h[(size_t)n * 64 + d];
    red[g][d] = acc;
    __syncthreads();
    if (tid < 64) {
        float t = red[0][tid] + red[1][tid] + red[2][tid] + red[3][tid];
        int cnt = hi - lo;
        feats[(size_t)c * 65 + tid] = t / (float)(cnt > 0 ? cnt : 1);
    }
}

// ---------------- head ----------------
__global__ __launch_bounds__(128) void k_head1(float* __restrict__ feats, const float* __restrict__ fap,
        const float* __restrict__ g, const float* __restrict__ b, float* __restrict__ featsp) {
    int tid = threadIdx.x;
    if (tid < CC) feats[(size_t)tid * 65 + 64] = fap[tid];
    __syncthreads();
    if (tid < 65) {
        float s = 0;
        for (int r = 0; r < CC; ++r) s += feats[r * 65 + tid];
        float m = s / (float)CC;
        float v = 0;
        for (int r = 0; r < CC; ++r) { float d = feats[r * 65 + tid] - m; v += d * d; }
        v /= (float)CC;
        float sc = g[tid] * rsqrtf(v + EPSBN);
        float sh = b[tid] - m * sc;
        for (int r = 0; r < CC; ++r)
            featsp[r * 65 + tid] = softplusf_(sc * feats[r * 65 + tid] + sh);
    }
}

__global__ __launch_bounds__(128) void k_head2(const float* __restrict__ featsp,
        const float* __restrict__ fc2w, const float* __restrict__ fc2b,
        const float* __restrict__ fc3w, const float* __restrict__ fc3b,
        float* __restrict__ out) {
    __shared__ float fr[65];
    __shared__ float red[128];
    int r = blockIdx.x, tid = threadIdx.x;
    if (tid < 65) fr[tid] = featsp[(size_t)r * 65 + tid];
    __syncthreads();
    float acc = fc2b[tid];
    for (int k = 0; k < 65; ++k) acc += fr[k] * fc2w[k * 128 + tid];
    red[tid] = softplusf_(acc) * fc3w[tid];
    __syncthreads();
    for (int st = 64; st > 0; st >>= 1) {
        if (tid < st) red[tid] += red[tid + st];
        __syncthreads();
    }
    if (tid == 0) out[r] = red[0] + fc3b[0];
}

extern "C" void kernel_launch(void* const* d_in, const int* in_sizes, int n_in,
                              void* d_out, int out_size, void* d_ws, size_t ws_size,
                              hipStream_t stream) {
    const float* site  = (const float*)d_in[0];
    const float* bondf = (const float*)d_in[1];
    const float* fap   = (const float*)d_in[2];
    const float* fc1w  = (const float*)d_in[3];
    const float* fc1b  = (const float*)d_in[4];
    const float* convw = (const float*)d_in[5];
    const float* convb = (const float*)d_in[6];
    const float* bn1g  = (const float*)d_in[7];
    const float* bn1b  = (const float*)d_in[8];
    const float* bn2g  = (const float*)d_in[9];
    const float* bn2b  = (const float*)d_in[10];
    const float* topg  = (const float*)d_in[11];
    const float* topb  = (const float*)d_in[12];
    const float* fc2w  = (const float*)d_in[13];
    const float* fc2b  = (const float*)d_in[14];
    const float* fc3w  = (const float*)d_in[15];
    const float* fc3b  = (const float*)d_in[16];
    const int*   bidx  = (const int*)d_in[17];
    const int*   cidx  = (const int*)d_in[18];
    float* out = (float*)d_out;

    char* w = (char*)d_ws;
    constexpr size_t SZ_H  = (size_t)NN * 64 * 4;
    constexpr size_t SZ_HP = (size_t)NN * 128 * 2;   // hi/hj bf16
    constexpr size_t OFF_H  = 0;
    constexpr size_t OFF_HI = OFF_H + SZ_H;
    constexpr size_t OFF_HJ = OFF_HI + SZ_HP;
    constexpr size_t OFF_S  = OFF_HJ + SZ_HP;
    constexpr size_t OFF_SCSH1 = OFF_S + SZ_H;
    constexpr size_t OFF_SCSH2 = OFF_SCSH1 + 1024;
    constexpr size_t OFF_P1 = OFF_SCSH2 + 512;
    constexpr size_t OFF_P2 = OFF_P1 + (size_t)G_BOND * 256 * 4;
    constexpr size_t OFF_PA = OFF_P2 + (size_t)G_APPLY * 128 * 4;
    constexpr size_t OFF_PB = OFF_PA + (size_t)RED1B * 256 * 4;
    constexpr size_t OFF_FE = OFF_PB + (size_t)RED2B * 128 * 4;
    constexpr size_t OFF_FP = OFF_FE + 128 * 65 * 4;
    constexpr size_t OFF_T  = ((OFF_FP + 128 * 65 * 4) + 255) & ~(size_t)255;
    constexpr size_t OFF_BFQ = OFF_T + (size_t)NBOND * 128 * 2;
    constexpr size_t NEED_BFQ = OFF_BFQ + (size_t)NBOND * 64 * 2;

    float* h      = (float*)(w + OFF_H);
    unsigned short* hi = (unsigned short*)(w + OFF_HI);
    unsigned short* hj = (unsigned short*)(w + OFF_HJ);
    float* sbuf   = (float*)(w + OFF_S);
    float* scsh1  = (float*)(w + OFF_SCSH1);
    float* scsh2  = (float*)(w + OFF_SCSH2);
    float* part1  = (float*)(w + OFF_P1);
    float* part2  = (float*)(w + OFF_P2);
    float* partA  = (float*)(w + OFF_PA);
    float* partB  = (float*)(w + OFF_PB);
    float* feats  = (float*)(w + OFF_FE);
    float* featsp = (float*)(w + OFF_FP);
    unsigned short* tbuf = (unsigned short*)(w + OFF_T);
    unsigned short* bfq  = (unsigned short*)(w + OFF_BFQ);

    const bool useq = (ws_size >= NEED_BFQ);

    if (useq) k_cvt<<<NBOND * 64 / (256 * 8), 256, 0, stream>>>(bondf, bfq);
    k_fc1<<<2500, 256, 0, stream>>>(site, fc1w, fc1b, h);
    for (int l = 0; l < LL; ++l) {
        const float* cw = convw + (size_t)l * 192 * 128;
        const float* cb = convb + l * 128;
        if (l == 0)
            k_proj<false><<<1250, 256, 0, stream>>>(h, sbuf, scsh2, cw, cb, hi, hj);
        else
            k_proj<true><<<1250, 256, 0, stream>>>(h, sbuf, scsh2, cw, cb, hi, hj);
        if (useq)
            k_bond<true><<<G_BOND, 256, 0, stream>>>(bondf, bfq, cw + 128 * 128, hi, hj, bidx, tbuf, part1);
        else
            k_bond<false><<<G_BOND, 256, 0, stream>>>(bondf, bfq, cw + 128 * 128, hi, hj, bidx, tbuf, part1);
        k_red1<<<RED1B, 256, 0, stream>>>(part1, partA);
        k_fin1<<<1, 1024, 0, stream>>>(partA, bn1g + l * 128, bn1b + l * 128, scsh1);
        k_apply<<<G_APPLY, 256, 0, stream>>>(tbuf, scsh1, sbuf, part2);
        k_red2<<<RED2B, 128, 0, stream>>>(part2, partB);
        k_fin2<<<1, 1024, 0, stream>>>(partB, bn2g + l * 64, bn2b + l * 64, scsh2);
    }
    k_upd<<<2500, 256, 0, stream>>>(h, sbuf, scsh2);   // layer-2 update before pooling
    k_pool<<<128, 256, 0, stream>>>(h, cidx, feats);
    k_head1<<<1, 128, 0, stream>>>(feats, fap, topg, topb, featsp);
    k_head2<<<128, 128, 0, stream>>>(featsp, fc2w, fc2b, fc3w, fc3b, out);
}

// Round 13
// 466.907 us; speedup vs baseline: 1.7380x; 1.0558x over previous
//
#include <hip/hip_runtime.h>
#include <hip/hip_bf16.h>

// CGCNN forward. Materialize-tbuf + swapped-operand MFMA + staged writeout + gather-hoisted k_bond.
// r13: BN finalize fused into consumers (k_apply recomputes scsh1 from L2-resident partA;
//      k_proj<FUSED> recomputes scsh2 from partB) -> 6 dispatches/layer, -5 total.
// r12: k_upd fused into next-layer k_proj; G_BOND=1024 (resident-exact).
// r10: parallel two-stage BN reductions. r9: gathers issued at interval START.
// r7: no direct scatter stores. r4: no min-waves clamp. r6: no analytic-mean prologue.

#define NN 40000
#define MM 12
#define AA 64
#define LL 3
#define CC 128
#define F0C 92
#define NBOND (NN*MM)
#define EPSBN 1e-5f

#define G_BOND 1024     // resident-exact; 7500 tiles grid-strided
#define NTILE 7500
#define G_APPLY 1250
#define RED1B 128       // part1 rows 1024 -> 128 blocks x 8 rows
#define RED2B 125       // part2 rows 1250 -> 125 blocks x 10 rows

#define L2E 1.4426950408889634f
#define LN2 0.6931471805599453f

typedef __attribute__((ext_vector_type(8))) short bf16x8;
typedef __attribute__((ext_vector_type(4))) float f32x4;

__device__ __forceinline__ float softplusf_(float x) {
    float e = __builtin_amdgcn_exp2f(-fabsf(x) * L2E);
    return fmaxf(x, 0.f) + __builtin_amdgcn_logf(1.f + e) * LN2;
}
__device__ __forceinline__ float sigmoidf_(float x) {
    return __builtin_amdgcn_rcpf(1.f + __builtin_amdgcn_exp2f(-x * L2E));
}
__device__ __forceinline__ unsigned short f2bf(float f) {
    unsigned int u = __float_as_uint(f);
    unsigned int r = (u + 0x7fffu + ((u >> 16) & 1u)) >> 16;
    return (unsigned short)r;
}
__device__ __forceinline__ float bf2f(unsigned short s) {
    return __uint_as_float(((unsigned int)s) << 16);
}

// ---------------- bond features f32 -> bf16, once ----------------
__global__ __launch_bounds__(256) void k_cvt(const float* __restrict__ in,
        unsigned short* __restrict__ out) {
    size_t i = ((size_t)blockIdx.x * 256 + threadIdx.x) * 8;
    float4 a = *(const float4*)&in[i];
    float4 b = *(const float4*)&in[i + 4];
    ushort4 ua, ub;
    ua.x = f2bf(a.x); ua.y = f2bf(a.y); ua.z = f2bf(a.z); ua.w = f2bf(a.w);
    ub.x = f2bf(b.x); ub.y = f2bf(b.y); ub.z = f2bf(b.z); ub.w = f2bf(b.w);
    *(ushort4*)&out[i] = ua;
    *(ushort4*)&out[i + 4] = ub;
}

// ---------------- fc1 ----------------
__global__ __launch_bounds__(256) void k_fc1(const float* __restrict__ site,
        const float* __restrict__ w, const float* __restrict__ b,
        float* __restrict__ h) {
    __shared__ float w_s[F0C][AA];
    __shared__ float x_s[16][F0C];
    int tid = threadIdx.x;
    for (int i = tid; i < F0C * AA; i += 256) w_s[i / AA][i % AA] = w[i];
    int n0 = blockIdx.x * 16;
    for (int i = tid; i < 16 * F0C; i += 256) x_s[i / F0C][i % F0C] = site[(size_t)n0 * F0C + i];
    __syncthreads();
    int d = tid & 63, ng = tid >> 6;
    float bb = b[d];
    float acc[4] = {bb, bb, bb, bb};
    #pragma unroll 4
    for (int k = 0; k < F0C; ++k) {
        float wv = w_s[k][d];
        acc[0] += x_s[ng][k] * wv;
        acc[1] += x_s[ng + 4][k] * wv;
        acc[2] += x_s[ng + 8][k] * wv;
        acc[3] += x_s[ng + 12][k] * wv;
    }
    #pragma unroll
    for (int rr = 0; rr < 4; ++rr)
        h[(size_t)(n0 + ng + rr * 4) * AA + d] = acc[rr];
}

// ---------------- proj (optionally fused with prev layer's h-update + bn2 finalize) ----------------
template<bool FUSED>
__global__ __launch_bounds__(256) void k_proj(float* __restrict__ h,
        const float* __restrict__ sbuf, const float* __restrict__ partB,
        const float* __restrict__ g2, const float* __restrict__ b2,
        const float* __restrict__ convw, const float* __restrict__ convb,
        unsigned short* __restrict__ hi, unsigned short* __restrict__ hj) {
    __shared__ float w_s[64][256];
    __shared__ float hT[64][36];
    __shared__ float sm2[128];
    __shared__ float scsh2_s[128];
    int tid = threadIdx.x;
    int row0 = blockIdx.x * 32;
    for (int i = tid; i < 64 * 256; i += 256) {
        int k = i >> 8, c = i & 255;
        w_s[k][c] = convw[(size_t)((c < 128 ? k : 64 + k)) * 128 + (c & 127)];
    }
    if constexpr (FUSED) {
        // finalize bn2 from partB [RED2B][128] (L2-resident), ILP-4
        if (tid < 128) {
            float a0 = 0.f, a1 = 0.f, a2 = 0.f, a3 = 0.f;
            int r = 0;
            for (; r + 3 < RED2B; r += 4) {
                a0 += partB[(size_t)r * 128 + tid];
                a1 += partB[(size_t)(r + 1) * 128 + tid];
                a2 += partB[(size_t)(r + 2) * 128 + tid];
                a3 += partB[(size_t)(r + 3) * 128 + tid];
            }
            for (; r < RED2B; ++r) a0 += partB[(size_t)r * 128 + tid];
            sm2[tid] = a0 + a1 + a2 + a3;
        }
        __syncthreads();
        if (tid < 64) {
            float m = sm2[tid] / (float)NN;
            float v = sm2[64 + tid] / (float)NN - m * m;
            float sc = g2[tid] * rsqrtf(v + EPSBN);
            scsh2_s[tid] = sc;
            scsh2_s[64 + tid] = b2[tid] - m * sc;
        }
        __syncthreads();
        int r = tid >> 3, k8 = (tid & 7) * 8;
        int n = row0 + r;
        float4 h0 = *(const float4*)&h[(size_t)n * 64 + k8];
        float4 h1 = *(const float4*)&h[(size_t)n * 64 + k8 + 4];
        float4 s0 = *(const float4*)&sbuf[(size_t)n * 64 + k8];
        float4 s1 = *(const float4*)&sbuf[(size_t)n * 64 + k8 + 4];
        float hv[8] = {h0.x, h0.y, h0.z, h0.w, h1.x, h1.y, h1.z, h1.w};
        float sv[8] = {s0.x, s0.y, s0.z, s0.w, s1.x, s1.y, s1.z, s1.w};
        float ov[8];
        #pragma unroll
        for (int j = 0; j < 8; ++j) {
            ov[j] = softplusf_(hv[j] + scsh2_s[k8 + j] * sv[j] + scsh2_s[64 + k8 + j]);
            hT[k8 + j][r] = ov[j];
        }
        *(float4*)&h[(size_t)n * 64 + k8]     = make_float4(ov[0], ov[1], ov[2], ov[3]);
        *(float4*)&h[(size_t)n * 64 + k8 + 4] = make_float4(ov[4], ov[5], ov[6], ov[7]);
    } else {
        for (int i = tid; i < 2048; i += 256) {
            int r = i >> 6, k = i & 63;
            hT[k][r] = h[(size_t)(row0 + r) * 64 + k];
        }
    }
    __syncthreads();
    int c0 = (tid & 63) * 4;
    int r0 = (tid >> 6) * 8;
    float acc[8][4];
    #pragma unroll
    for (int r = 0; r < 8; ++r)
        #pragma unroll
        for (int i = 0; i < 4; ++i) acc[r][i] = 0.f;
    #pragma unroll 4
    for (int k = 0; k < 64; ++k) {
        float4 w4 = *(const float4*)&w_s[k][c0];
        float4 ha = *(const float4*)&hT[k][r0];
        float4 hb = *(const float4*)&hT[k][r0 + 4];
        float wv[4] = {w4.x, w4.y, w4.z, w4.w};
        float hv[8] = {ha.x, ha.y, ha.z, ha.w, hb.x, hb.y, hb.z, hb.w};
        #pragma unroll
        for (int r = 0; r < 8; ++r)
            #pragma unroll
            for (int i = 0; i < 4; ++i) acc[r][i] += hv[r] * wv[i];
    }
    bool isHi = (c0 < 128);
    int cc = isHi ? c0 : c0 - 128;
    float4 cb4 = make_float4(0.f, 0.f, 0.f, 0.f);
    if (isHi) cb4 = *(const float4*)&convb[c0];
    unsigned short* dst = isHi ? hi : hj;
    #pragma unroll
    for (int r = 0; r < 8; ++r) {
        int n = row0 + r0 + r;
        ushort4 o;
        o.x = f2bf(acc[r][0] + cb4.x);
        o.y = f2bf(acc[r][1] + cb4.y);
        o.z = f2bf(acc[r][2] + cb4.z);
        o.w = f2bf(acc[r][3] + cb4.w);
        *(ushort4*)&dst[(size_t)n * 128 + cc] = o;
    }
}

// ---------------- bond GEMM, gather-hoisted pipeline ----------------
template<bool BFQ>
__global__ __launch_bounds__(256) void k_bond(const float* __restrict__ bf,
        const unsigned short* __restrict__ bfq,
        const float* __restrict__ wb,
        const unsigned short* __restrict__ hi, const unsigned short* __restrict__ hj,
        const int* __restrict__ bidx,
        unsigned short* __restrict__ tbuf,
        float* __restrict__ part1) {
    __shared__ __align__(16) char buf0[128 * 72 * 2];      // wbT preload, then t_lds[64][140]
    __shared__ __align__(16) char bufA[2][64 * 76 * 2];    // double-buffered A; red overlays [0]
    auto wbT   = (unsigned short(*)[72])buf0;
    auto t_lds = (unsigned short(*)[140])buf0;
    auto red   = (float(*)[128])bufA[0];

    int tid = threadIdx.x;
    int lane = tid & 63, w = tid >> 6;
    int l15 = lane & 15, l4 = lane >> 4;

    for (int i = tid; i < 64 * 128; i += 256) {
        int k = i >> 7, c = i & 127;
        wbT[c][k] = f2bf(wb[i]);
    }
    __syncthreads();
    bf16x8 bfr[2][8];
    #pragma unroll
    for (int kh = 0; kh < 2; ++kh)
        #pragma unroll
        for (int ct = 0; ct < 8; ++ct)
            bfr[kh][ct] = *(const bf16x8*)&wbT[ct * 16 + l15][kh * 32 + l4 * 8];

    int myb = w * 16 + l15;                    // MFMA-phase bond
    int wr = tid >> 4, wc8 = (tid & 15) * 8;   // writeout-phase coords
    int sr = tid >> 3, sk8 = (tid & 7) * 8;    // staging coords
    float suml[8], sql[8];
    #pragma unroll
    for (int k = 0; k < 8; ++k) { suml[k] = 0.f; sql[k] = 0.f; }

    // prologue: stage tile0 into A[0]; prefetch bidx for tile0
    int j4[4];
    {
        int bond0 = blockIdx.x * 64;
        #pragma unroll
        for (int rr = 0; rr < 4; ++rr) j4[rr] = bidx[bond0 + wr + rr * 16];
        auto A0 = (unsigned short(*)[76])bufA[0];
        if constexpr (BFQ) {
            bf16x8 s0 = *(const bf16x8*)&bfq[((size_t)(bond0 + sr)) * 64 + sk8];
            bf16x8 s1 = *(const bf16x8*)&bfq[((size_t)(bond0 + sr + 32)) * 64 + sk8];
            *(bf16x8*)&A0[sr][sk8] = s0;
            *(bf16x8*)&A0[sr + 32][sk8] = s1;
        } else {
            #pragma unroll
            for (int ii = 0; ii < 2; ++ii) {
                int r = sr + ii * 32;
                float4 v0 = *(const float4*)&bf[((size_t)(bond0 + r)) * 64 + sk8];
                float4 v1 = *(const float4*)&bf[((size_t)(bond0 + r)) * 64 + sk8 + 4];
                ushort4 ua, ub;
                ua.x = f2bf(v0.x); ua.y = f2bf(v0.y); ua.z = f2bf(v0.z); ua.w = f2bf(v0.w);
                ub.x = f2bf(v1.x); ub.y = f2bf(v1.y); ub.z = f2bf(v1.z); ub.w = f2bf(v1.w);
                *(ushort4*)&A0[r][sk8] = ua;
                *(ushort4*)&A0[r][sk8 + 4] = ub;
            }
        }
    }
    __syncthreads();   // A[0] ready; bfr's wbT reads complete before t_lds overlays

    int it = 0;
    for (int tile = blockIdx.x; tile < NTILE; tile += G_BOND, ++it) {
        int bond0 = tile * 64;
        auto Acur = (unsigned short(*)[76])bufA[it & 1];
        auto Anxt = (unsigned short(*)[76])bufA[(it & 1) ^ 1];
        bool has_next = (tile + G_BOND < NTILE);

        // I1a: issue current-tile hj gathers (random rows; overlap everything below)
        bf16x8 hj8[4];
        #pragma unroll
        for (int rr = 0; rr < 4; ++rr)
            hj8[rr] = *(const bf16x8*)&hj[(size_t)j4[rr] * 128 + wc8];

        // I1b: issue next-tile staging loads + bidx prefetch
        bf16x8 st0, st1;
        float4 nf0[2], nf1[2];
        int j4n[4];
        if (has_next) {
            int nb0 = (tile + G_BOND) * 64;
            if constexpr (BFQ) {
                st0 = *(const bf16x8*)&bfq[((size_t)(nb0 + sr)) * 64 + sk8];
                st1 = *(const bf16x8*)&bfq[((size_t)(nb0 + sr + 32)) * 64 + sk8];
            } else {
                #pragma unroll
                for (int ii = 0; ii < 2; ++ii) {
                    int r = sr + ii * 32;
                    nf0[ii] = *(const float4*)&bf[((size_t)(nb0 + r)) * 64 + sk8];
                    nf1[ii] = *(const float4*)&bf[((size_t)(nb0 + r)) * 64 + sk8 + 4];
                }
            }
            #pragma unroll
            for (int rr = 0; rr < 4; ++rr) j4n[rr] = bidx[nb0 + wr + rr * 16];
        }

        // I1c: MFMA current tile
        f32x4 acc[8];
        #pragma unroll
        for (int ct = 0; ct < 8; ++ct) acc[ct] = (f32x4){0.f, 0.f, 0.f, 0.f};
        #pragma unroll
        for (int kh = 0; kh < 2; ++kh) {
            bf16x8 a = *(const bf16x8*)&Acur[myb][kh * 32 + l4 * 8];
            #pragma unroll
            for (int ct = 0; ct < 8; ++ct)
                acc[ct] = __builtin_amdgcn_mfma_f32_16x16x32_bf16(bfr[kh][ct], a, acc[ct], 0, 0, 0);
        }

        // I1d: stage raw acc (bf16) into t_lds
        #pragma unroll
        for (int ct = 0; ct < 8; ++ct) {
            ushort4 o;
            o.x = f2bf(acc[ct][0]); o.y = f2bf(acc[ct][1]);
            o.z = f2bf(acc[ct][2]); o.w = f2bf(acc[ct][3]);
            *(ushort4*)&t_lds[myb][ct * 16 + l4 * 4] = o;
        }
        __syncthreads();

        // I2a: writeout — t_lds + L1-hot hi + resident hj8; 256B store runs
        #pragma unroll
        for (int rr = 0; rr < 4; ++rr) {
            int r = wr + rr * 16;
            int bond = bond0 + r;
            int n = bond / MM;
            bf16x8 g8  = *(const bf16x8*)&t_lds[r][wc8];
            bf16x8 hi8 = *(const bf16x8*)&hi[(size_t)n * 128 + wc8];
            bf16x8 o;
            #pragma unroll
            for (int k = 0; k < 8; ++k) {
                float t = bf2f((unsigned short)g8[k]) + bf2f((unsigned short)hi8[k])
                        + bf2f((unsigned short)hj8[rr][k]);
                suml[k] += t;
                sql[k] += t * t;
                o[k] = (short)f2bf(t);
            }
            *(bf16x8*)&tbuf[(size_t)bond * 128 + wc8] = o;
        }

        // I2b: commit staged regs into A[next]; roll bidx prefetch
        if (has_next) {
            if constexpr (BFQ) {
                *(bf16x8*)&Anxt[sr][sk8] = st0;
                *(bf16x8*)&Anxt[sr + 32][sk8] = st1;
            } else {
                #pragma unroll
                for (int ii = 0; ii < 2; ++ii) {
                    int r = sr + ii * 32;
                    ushort4 ua, ub;
                    ua.x = f2bf(nf0[ii].x); ua.y = f2bf(nf0[ii].y);
                    ua.z = f2bf(nf0[ii].z); ua.w = f2bf(nf0[ii].w);
                    ub.x = f2bf(nf1[ii].x); ub.y = f2bf(nf1[ii].y);
                    ub.z = f2bf(nf1[ii].z); ub.w = f2bf(nf1[ii].w);
                    *(ushort4*)&Anxt[r][sk8] = ua;
                    *(ushort4*)&Anxt[r][sk8 + 4] = ub;
                }
            }
            #pragma unroll
            for (int rr = 0; rr < 4; ++rr) j4[rr] = j4n[rr];
        }
        __syncthreads();
    }

    // bn1 partials: thread owns cols wc8..wc8+7; reduce over 16 row-groups
    #pragma unroll
    for (int k = 0; k < 8; ++k) red[wr][wc8 + k] = suml[k];
    __syncthreads();
    if (tid < 128) {
        float s = 0.f;
        #pragma unroll
        for (int g = 0; g < 16; ++g) s += red[g][tid];
        part1[(size_t)blockIdx.x * 256 + tid] = s;
    }
    __syncthreads();
    #pragma unroll
    for (int k = 0; k < 8; ++k) red[wr][wc8 + k] = sql[k];
    __syncthreads();
    if (tid < 128) {
        float s = 0.f;
        #pragma unroll
        for (int g = 0; g < 16; ++g) s += red[g][tid];
        part1[(size_t)blockIdx.x * 256 + 128 + tid] = s;
    }
}

// ---------------- stage-A reductions (parallel) ----------------
__global__ __launch_bounds__(256) void k_red1(const float* __restrict__ in, float* __restrict__ out) {
    int tid = threadIdx.x, b = blockIdx.x;
    float acc = 0.f;
    for (int r = b * 8; r < b * 8 + 8; ++r) acc += in[(size_t)r * 256 + tid];
    out[(size_t)b * 256 + tid] = acc;
}
__global__ __launch_bounds__(128) void k_red2(const float* __restrict__ in, float* __restrict__ out) {
    int tid = threadIdx.x, b = blockIdx.x;
    float acc = 0.f;
    for (int r = b * 10; r < b * 10 + 10; ++r) acc += in[(size_t)r * 128 + tid];
    out[(size_t)b * 128 + tid] = acc;
}

// ---------------- finalize bn2 (final layer only) ----------------
__global__ __launch_bounds__(1024) void k_fin2(const float* __restrict__ partB,
        const float* __restrict__ g, const float* __restrict__ b, float* __restrict__ scsh2) {
    __shared__ float sm[8][128];
    int tid = threadIdx.x;
    int rg = tid >> 7, c = tid & 127;
    float acc = 0.f;
    for (int r = rg; r < RED2B; r += 8) acc += partB[(size_t)r * 128 + c];
    sm[rg][c] = acc;
    __syncthreads();
    if (tid < 128) {
        float s = 0.f;
        #pragma unroll
        for (int g8 = 0; g8 < 8; ++g8) s += sm[g8][tid];
        sm[0][tid] = s;
    }
    __syncthreads();
    if (tid < 64) {
        float m = sm[0][tid] / (float)NN;
        float v = sm[0][64 + tid] / (float)NN - m * m;
        float sc = g[tid] * rsqrtf(v + EPSBN);
        scsh2[tid] = sc;
        scsh2[64 + tid] = b[tid] - m * sc;
    }
}

// ---------------- apply: fused bn1 finalize + gate + m-reduce + bn2 partials ----------------
__global__ __launch_bounds__(256) void k_apply(const unsigned short* __restrict__ tbuf,
        const float* __restrict__ partA,
        const float* __restrict__ g1, const float* __restrict__ b1,
        float* __restrict__ s_out, float* __restrict__ part2) {
    __shared__ float red[32][64];
    __shared__ float sm1[256];
    __shared__ float scsh_s[256];
    int tid = threadIdx.x;
    // finalize bn1 from partA [RED1B][256] (L2-resident), ILP-4
    {
        float a0 = 0.f, a1 = 0.f, a2 = 0.f, a3 = 0.f;
        for (int r = 0; r < RED1B; r += 4) {
            a0 += partA[(size_t)r * 256 + tid];
            a1 += partA[(size_t)(r + 1) * 256 + tid];
            a2 += partA[(size_t)(r + 2) * 256 + tid];
            a3 += partA[(size_t)(r + 3) * 256 + tid];
        }
        sm1[tid] = a0 + a1 + a2 + a3;
    }
    __syncthreads();
    if (tid < 128) {
        float m = sm1[tid] / (float)NBOND;
        float v = sm1[128 + tid] / (float)NBOND - m * m;
        float sc = g1[tid] * rsqrtf(v + EPSBN);
        scsh_s[tid] = sc;
        scsh_s[128 + tid] = b1[tid] - m * sc;
    }
    __syncthreads();

    int c8 = (tid & 7) * 8, sg = tid >> 3;
    float scf[8], shf[8], scc[8], shc[8];
    #pragma unroll
    for (int j = 0; j < 8; ++j) {
        scf[j] = scsh_s[c8 + j];       shf[j] = scsh_s[128 + c8 + j];
        scc[j] = scsh_s[64 + c8 + j];  shc[j] = scsh_s[192 + c8 + j];
    }
    float sum[8], sq[8];
    #pragma unroll
    for (int j = 0; j < 8; ++j) { sum[j] = 0.f; sq[j] = 0.f; }
    for (int q = blockIdx.x; q < NN / 32; q += G_APPLY) {
        int n = q * 32 + sg;
        const unsigned short* tb = tbuf + (size_t)n * (MM * 128);
        float sacc[8];
        #pragma unroll
        for (int j = 0; j < 8; ++j) sacc[j] = 0.f;
        #pragma unroll
        for (int m = 0; m < MM; ++m) {
            bf16x8 f8 = *(const bf16x8*)&tb[m * 128 + c8];
            bf16x8 s8 = *(const bf16x8*)&tb[m * 128 + 64 + c8];
            #pragma unroll
            for (int j = 0; j < 8; ++j) {
                float ff = bf2f((unsigned short)f8[j]);
                float ss = bf2f((unsigned short)s8[j]);
                sacc[j] += sigmoidf_(scf[j] * ff + shf[j]) * softplusf_(scc[j] * ss + shc[j]);
            }
        }
        float4 oa = make_float4(sacc[0], sacc[1], sacc[2], sacc[3]);
        float4 ob = make_float4(sacc[4], sacc[5], sacc[6], sacc[7]);
        *(float4*)&s_out[(size_t)n * 64 + c8] = oa;
        *(float4*)&s_out[(size_t)n * 64 + c8 + 4] = ob;
        #pragma unroll
        for (int j = 0; j < 8; ++j) { sum[j] += sacc[j]; sq[j] += sacc[j] * sacc[j]; }
    }
    #pragma unroll
    for (int j = 0; j < 8; ++j) red[sg][c8 + j] = sum[j];
    __syncthreads();
    if (tid < 64) {
        float t = 0.f;
        #pragma unroll
        for (int g = 0; g < 32; ++g) t += red[g][tid];
        part2[(size_t)blockIdx.x * 128 + tid] = t;
    }
    __syncthreads();
    #pragma unroll
    for (int j = 0; j < 8; ++j) red[sg][c8 + j] = sq[j];
    __syncthreads();
    if (tid < 64) {
        float t = 0.f;
        #pragma unroll
        for (int g = 0; g < 32; ++g) t += red[g][tid];
        part2[(size_t)blockIdx.x * 128 + 64 + tid] = t;
    }
}

// ---------------- standalone h = softplus(h + bn2(s))  (final layer only) ----------------
__global__ __launch_bounds__(256) void k_upd(float* __restrict__ h, const float* __restrict__ s,
        const float* __restrict__ scsh2) {
    size_t i = ((size_t)blockIdx.x * 256 + threadIdx.x) * 4;
    int c0 = (int)(i & 63);
    float4 hv = *(const float4*)&h[i];
    float4 sv = *(const float4*)&s[i];
    float4 o;
    o.x = softplusf_(hv.x + scsh2[c0 + 0] * sv.x + scsh2[64 + c0 + 0]);
    o.y = softplusf_(hv.y + scsh2[c0 + 1] * sv.y + scsh2[64 + c0 + 1]);
    o.z = softplusf_(hv.z + scsh2[c0 + 2] * sv.z + scsh2[64 + c0 + 2]);
    o.w = softplusf_(hv.w + scsh2[c0 + 3] * sv.w + scsh2[64 + c0 + 3]);
    *(float4*)&h[i] = o;
}

// ---------------- pooling ----------------
__device__ __forceinline__ int lbound(const int* a, int n, int v) {
    int lo = 0, hi = n;
    while (lo < hi) { int mid = (lo + hi) >> 1; if (a[mid] < v) lo = mid + 1; else hi = mid; }
    return lo;
}

__global__ __launch_bounds__(256) void k_pool(const float* __restrict__ h,
        const int* __restrict__ cidx, float* __restrict__ feats) {
    __shared__ float red[4][68];
    __shared__ int bounds[2];
    int c = blockIdx.x, tid = threadIdx.x;
    if (tid == 0) {
        bounds[0] = lbound(cidx, NN, c);
        bounds[1] = lbound(cidx, NN, c + 1);
    }
    __syncthreads();
    int lo = bounds[0], hi = bounds[1];
    int d = tid & 63, g = tid >> 6;
    float acc = 0;
    for (int n = lo + g; n < hi; n += 4) acc += h[(size_t)n * 64 + d];
    red[g][d] = acc;
    __syncthreads();
    if (tid < 64) {
        float t = red[0][tid] + red[1][tid] + red[2][tid] + red[3][tid];
        int cnt = hi - lo;
        feats[(size_t)c * 65 + tid] = t / (float)(cnt > 0 ? cnt : 1);
    }
}

// ---------------- head ----------------
__global__ __launch_bounds__(128) void k_head1(float* __restrict__ feats, const float* __restrict__ fap,
        const float* __restrict__ g, const float* __restrict__ b, float* __restrict__ featsp) {
    int tid = threadIdx.x;
    if (tid < CC) feats[(size_t)tid * 65 + 64] = fap[tid];
    __syncthreads();
    if (tid < 65) {
        float s = 0;
        for (int r = 0; r < CC; ++r) s += feats[r * 65 + tid];
        float m = s / (float)CC;
        float v = 0;
        for (int r = 0; r < CC; ++r) { float d = feats[r * 65 + tid] - m; v += d * d; }
        v /= (float)CC;
        float sc = g[tid] * rsqrtf(v + EPSBN);
        float sh = b[tid] - m * sc;
        for (int r = 0; r < CC; ++r)
            featsp[r * 65 + tid] = softplusf_(sc * feats[r * 65 + tid] + sh);
    }
}

__global__ __launch_bounds__(128) void k_head2(const float* __restrict__ featsp,
        const float* __restrict__ fc2w, const float* __restrict__ fc2b,
        const float* __restrict__ fc3w, const float* __restrict__ fc3b,
        float* __restrict__ out) {
    __shared__ float fr[65];
    __shared__ float red[128];
    int r = blockIdx.x, tid = threadIdx.x;
    if (tid < 65) fr[tid] = featsp[(size_t)r * 65 + tid];
    __syncthreads();
    float acc = fc2b[tid];
    for (int k = 0; k < 65; ++k) acc += fr[k] * fc2w[k * 128 + tid];
    red[tid] = softplusf_(acc) * fc3w[tid];
    __syncthreads();
    for (int st = 64; st > 0; st >>= 1) {
        if (tid < st) red[tid] += red[tid + st];
        __syncthreads();
    }
    if (tid == 0) out[r] = red[0] + fc3b[0];
}

extern "C" void kernel_launch(void* const* d_in, const int* in_sizes, int n_in,
                              void* d_out, int out_size, void* d_ws, size_t ws_size,
                              hipStream_t stream) {
    const float* site  = (const float*)d_in[0];
    const float* bondf = (const float*)d_in[1];
    const float* fap   = (const float*)d_in[2];
    const float* fc1w  = (const float*)d_in[3];
    const float* fc1b  = (const float*)d_in[4];
    const float* convw = (const float*)d_in[5];
    const float* convb = (const float*)d_in[6];
    const float* bn1g  = (const float*)d_in[7];
    const float* bn1b  = (const float*)d_in[8];
    const float* bn2g  = (const float*)d_in[9];
    const float* bn2b  = (const float*)d_in[10];
    const float* topg  = (const float*)d_in[11];
    const float* topb  = (const float*)d_in[12];
    const float* fc2w  = (const float*)d_in[13];
    const float* fc2b  = (const float*)d_in[14];
    const float* fc3w  = (const float*)d_in[15];
    const float* fc3b  = (const float*)d_in[16];
    const int*   bidx  = (const int*)d_in[17];
    const int*   cidx  = (const int*)d_in[18];
    float* out = (float*)d_out;

    char* w = (char*)d_ws;
    constexpr size_t SZ_H  = (size_t)NN * 64 * 4;
    constexpr size_t SZ_HP = (size_t)NN * 128 * 2;   // hi/hj bf16
    constexpr size_t OFF_H  = 0;
    constexpr size_t OFF_HI = OFF_H + SZ_H;
    constexpr size_t OFF_HJ = OFF_HI + SZ_HP;
    constexpr size_t OFF_S  = OFF_HJ + SZ_HP;
    constexpr size_t OFF_SCSH2 = OFF_S + SZ_H;
    constexpr size_t OFF_P1 = OFF_SCSH2 + 512;
    constexpr size_t OFF_P2 = OFF_P1 + (size_t)G_BOND * 256 * 4;
    constexpr size_t OFF_PA = OFF_P2 + (size_t)G_APPLY * 128 * 4;
    constexpr size_t OFF_PB = OFF_PA + (size_t)RED1B * 256 * 4;
    constexpr size_t OFF_FE = OFF_PB + (size_t)RED2B * 128 * 4;
    constexpr size_t OFF_FP = OFF_FE + 128 * 65 * 4;
    constexpr size_t OFF_T  = ((OFF_FP + 128 * 65 * 4) + 255) & ~(size_t)255;
    constexpr size_t OFF_BFQ = OFF_T + (size_t)NBOND * 128 * 2;
    constexpr size_t NEED_BFQ = OFF_BFQ + (size_t)NBOND * 64 * 2;

    float* h      = (float*)(w + OFF_H);
    unsigned short* hi = (unsigned short*)(w + OFF_HI);
    unsigned short* hj = (unsigned short*)(w + OFF_HJ);
    float* sbuf   = (float*)(w + OFF_S);
    float* scsh2  = (float*)(w + OFF_SCSH2);
    float* part1  = (float*)(w + OFF_P1);
    float* part2  = (float*)(w + OFF_P2);
    float* partA  = (float*)(w + OFF_PA);
    float* partB  = (float*)(w + OFF_PB);
    float* feats  = (float*)(w + OFF_FE);
    float* featsp = (float*)(w + OFF_FP);
    unsigned short* tbuf = (unsigned short*)(w + OFF_T);
    unsigned short* bfq  = (unsigned short*)(w + OFF_BFQ);

    const bool useq = (ws_size >= NEED_BFQ);

    if (useq) k_cvt<<<NBOND * 64 / (256 * 8), 256, 0, stream>>>(bondf, bfq);
    k_fc1<<<2500, 256, 0, stream>>>(site, fc1w, fc1b, h);
    for (int l = 0; l < LL; ++l) {
        const float* cw = convw + (size_t)l * 192 * 128;
        const float* cb = convb + l * 128;
        if (l == 0)
            k_proj<false><<<1250, 256, 0, stream>>>(h, sbuf, partB,
                bn2g, bn2b, cw, cb, hi, hj);
        else
            k_proj<true><<<1250, 256, 0, stream>>>(h, sbuf, partB,
                bn2g + (l - 1) * 64, bn2b + (l - 1) * 64, cw, cb, hi, hj);
        if (useq)
            k_bond<true><<<G_BOND, 256, 0, stream>>>(bondf, bfq, cw + 128 * 128, hi, hj, bidx, tbuf, part1);
        else
            k_bond<false><<<G_BOND, 256, 0, stream>>>(bondf, bfq, cw + 128 * 128, hi, hj, bidx, tbuf, part1);
        k_red1<<<RED1B, 256, 0, stream>>>(part1, partA);
        k_apply<<<G_APPLY, 256, 0, stream>>>(tbuf, partA, bn1g + l * 128, bn1b + l * 128,
                                             sbuf, part2);
        k_red2<<<RED2B, 128, 0, stream>>>(part2, partB);
    }
    k_fin2<<<1, 1024, 0, stream>>>(partB, bn2g + 2 * 64, bn2b + 2 * 64, scsh2);
    k_upd<<<2500, 256, 0, stream>>>(h, sbuf, scsh2);
    k_pool<<<128, 256, 0, stream>>>(h, cidx, feats);
    k_head1<<<1, 128, 0, stream>>>(feats, fap, topg, topb, featsp);
    k_head2<<<128, 128, 0, stream>>>(featsp, fc2w, fc2b, fc3w, fc3b, out);
}